// Round 11
// baseline (916.855 us; speedup 1.0000x reference)
//
#include <hip/hip_runtime.h>
#include <math.h>

typedef unsigned short u16;
typedef unsigned int u32;
typedef __attribute__((ext_vector_type(8))) short bfrag;   // 8 bf16 (4 VGPRs)
typedef __attribute__((ext_vector_type(4))) float f32x4;

// fast gelu: erf(z) via Abramowitz-Stegun 7.1.26 (|eps|<=1.5e-7), z = x/sqrt(2)
__device__ __forceinline__ float gelu_f(float x){
  float z = fabsf(x) * 0.70710678118654752440f;
  float t = __builtin_amdgcn_rcpf(1.0f + 0.3275911f*z);
  float p = t*(0.254829592f + t*(-0.284496736f + t*(1.421413741f
            + t*(-1.453152027f + t*1.061405429f))));
  float e = __expf(-z*z);
  float er = copysignf(1.0f - p*e, x);
  return 0.5f * x * (1.0f + er);
}
__device__ __forceinline__ u16 f2bf(float f){
  union { float f; unsigned int i; } c; c.f = f;
  unsigned int i = c.i;
  return (u16)((i + 0x7FFFu + ((i >> 16) & 1u)) >> 16);
}
__device__ __forceinline__ float bf2f(u16 u){
  union { unsigned int i; float f; } c; c.i = ((unsigned int)u) << 16; return c.f;
}

// async global->LDS DMA, 16B per lane. LDS dest = wave-uniform base + lane*16B.
__device__ __forceinline__ void gload_lds16(const u16* g, u16* l){
  __builtin_amdgcn_global_load_lds(
      (const __attribute__((address_space(1))) u32*)(g),
      (__attribute__((address_space(3))) u32*)(l),
      16, 0, 0);
}

struct F8 { float v[8]; };
__device__ __forceinline__ F8 load8f(const float* p){
  float4 a = *(const float4*)p; float4 b = *(const float4*)(p + 4);
  F8 r; r.v[0]=a.x; r.v[1]=a.y; r.v[2]=a.z; r.v[3]=a.w;
  r.v[4]=b.x; r.v[5]=b.y; r.v[6]=b.z; r.v[7]=b.w; return r;
}

#define PRE_STRIDE 4624

// ============ k0 phase A: mlp_s (2->256->2) + residual -> GT1 ==============
__global__ __launch_bounds__(256) void k0a_mlps(
    const float* __restrict__ gtok,
    const float* __restrict__ ws1_w, const float* __restrict__ ws1_b,
    const float* __restrict__ ws2_w, const float* __restrict__ ws2_b,
    float* __restrict__ GT1)
{
  __shared__ float sw1[256][2]; __shared__ float sb1[256];
  __shared__ float sw2[2][256];
  const int b = blockIdx.x;
  const int t = threadIdx.x;
  sw1[t][0] = ws1_w[2*t]; sw1[t][1] = ws1_w[2*t+1];
  sb1[t] = ws1_b[t];
  sw2[0][t] = ws2_w[t]; sw2[1][t] = ws2_w[256+t];
  __syncthreads();
  const int j = blockIdx.y*256 + t;
  const float a0 = gtok[b*1024 + 2*j], a1 = gtok[b*1024 + 2*j + 1];
  float s0 = ws2_b[0], s1 = ws2_b[1];
  #pragma unroll 4
  for (int o = 0; o < 256; ++o){
    float h = gelu_f(sw1[o][0]*a0 + sw1[o][1]*a1 + sb1[o]);
    s0 += sw2[0][o]*h; s1 += sw2[1][o]*h;
  }
  GT1[b*1024 + 2*j]     = a0 + s0;
  GT1[b*1024 + 2*j + 1] = a1 + s1;
}

// ============ k0 phase B: fc1 of mlp_c (512->2048) -> HID ==================
__global__ __launch_bounds__(256) void k0b_fc1(
    const float* __restrict__ GT1,
    const float* __restrict__ wc1_w, const float* __restrict__ wc1_b,
    float* __restrict__ HID)
{
  __shared__ float g[1024];
  const int b = blockIdx.x;
  const int t = threadIdx.x;
  for (int i = t; i < 1024; i += 256) g[i] = GT1[b*1024 + i];
  __syncthreads();
  const int o = blockIdx.y*256 + t;
  const float* wr = wc1_w + (size_t)o*512;
  float acc0 = wc1_b[o], acc1 = acc0;
  for (int d = 0; d < 512; d += 8){
    F8 w = load8f(wr + d);
    #pragma unroll
    for (int i = 0; i < 8; ++i){
      acc0 += w.v[i]*g[(d+i)*2];
      acc1 += w.v[i]*g[(d+i)*2+1];
    }
  }
  HID[b*4096 + o]        = gelu_f(acc0);
  HID[b*4096 + 2048 + o] = gelu_f(acc1);
}

// ============ k0 phase C: fc2 of mlp_c (2048->512) + residual -> GT2 =======
__global__ __launch_bounds__(256) void k0c_fc2(
    const float* __restrict__ GT1, const float* __restrict__ HID,
    const float* __restrict__ wc2_w, const float* __restrict__ wc2_b,
    float* __restrict__ GT2)
{
  __shared__ float h0[2048], h1[2048];
  const int b = blockIdx.x;
  const int t = threadIdx.x;
  for (int i = t; i < 2048; i += 256){
    h0[i] = HID[b*4096 + i]; h1[i] = HID[b*4096 + 2048 + i];
  }
  __syncthreads();
  const int d = blockIdx.y*256 + t;
  const float* wr = wc2_w + (size_t)d*2048;
  float acc0 = wc2_b[d], acc1 = acc0;
  for (int o = 0; o < 2048; o += 8){
    F8 w = load8f(wr + o);
    #pragma unroll
    for (int i = 0; i < 8; ++i){
      acc0 += w.v[i]*h0[o+i];
      acc1 += w.v[i]*h1[o+i];
    }
  }
  GT2[b*1024 + 2*d]     = GT1[b*1024 + 2*d]     + acc0;
  GT2[b*1024 + 2*d + 1] = GT1[b*1024 + 2*d + 1] + acc1;
}

// ============ k0 phase D: k,v -> dk, dv, v1l ================================
__global__ __launch_bounds__(256) void k0d_kv(
    const float* __restrict__ GT2,
    const float* __restrict__ k_w,
    const float* __restrict__ v_w, const float* __restrict__ v_b,
    float* __restrict__ DK, float* __restrict__ DV, float* __restrict__ V1L)
{
  __shared__ float g[1024];
  const int b = blockIdx.x;
  const int t = threadIdx.x;
  for (int i = t; i < 1024; i += 256) g[i] = GT2[b*1024 + i];
  __syncthreads();
  const int c = blockIdx.y*256 + t;
  const float* kr = k_w + (size_t)c*512;
  const float* vr = v_w + (size_t)c*512;
  float k0a=0.f,k1a=0.f,v0a=0.f,v1a=0.f;
  for (int d = 0; d < 512; d += 8){
    F8 kw = load8f(kr + d); F8 vw = load8f(vr + d);
    #pragma unroll
    for (int i = 0; i < 8; ++i){
      float g0 = g[(d+i)*2], g1 = g[(d+i)*2+1];
      k0a += kw.v[i]*g0; k1a += kw.v[i]*g1;
      v0a += vw.v[i]*g0; v1a += vw.v[i]*g1;
    }
  }
  DK[b*512 + c]  = k0a - k1a;
  DV[b*512 + c]  = v0a - v1a;
  V1L[b*512 + c] = v1a + v_b[c];
}

// ============ k0 phase E: wdiff + beta4 -> PRE ==============================
__global__ __launch_bounds__(256) void k0e_qpre(
    const float* __restrict__ DK,
    const float* __restrict__ q_w, const float* __restrict__ q_b,
    float* __restrict__ PRE)
{
  __shared__ float dkl[512];
  const int b = blockIdx.x;
  const int t = threadIdx.x;
  for (int i = t; i < 512; i += 256) dkl[i] = DK[b*512 + i];
  __syncthreads();
  const int i = blockIdx.y*256 + t;
  float w0=0.f,w1=0.f,w2=0.f,w3=0.f;
  for (int c = 0; c < 512; c += 4){
    w0 += dkl[c]  *q_w[(size_t)(c)  *512 + i];
    w1 += dkl[c+1]*q_w[(size_t)(c+1)*512 + i];
    w2 += dkl[c+2]*q_w[(size_t)(c+2)*512 + i];
    w3 += dkl[c+3]*q_w[(size_t)(c+3)*512 + i];
  }
  float* P = PRE + (size_t)b * PRE_STRIDE;
  P[0*512+i]=w0; P[1*512+i]=w1; P[2*512+i]=w2; P[3*512+i]=w3;
  if (blockIdx.y == 0 && t < 4){
    float bsum = 0.f;
    for (int c = t; c < 512; c += 4) bsum += dkl[c]*q_b[c];
    P[2048 + t] = bsum;
  }
}

// ============ k0 phase F: base + M -> PRE ===================================
__global__ __launch_bounds__(256) void k0f_mpre(
    const float* __restrict__ DV, const float* __restrict__ V1L,
    const float* __restrict__ merge_w, const float* __restrict__ merge_b,
    float* __restrict__ PRE)
{
  __shared__ float dvl[512], v1ll[512];
  const int b = blockIdx.x;
  const int t = threadIdx.x;
  for (int i = t; i < 512; i += 256){
    dvl[i] = DV[b*512 + i]; v1ll[i] = V1L[b*512 + i];
  }
  __syncthreads();
  const int r = blockIdx.y*256 + t;
  const float* mw = merge_w + (size_t)r*512;
  float ab = merge_b[r];
  float mh[4] = {0.f,0.f,0.f,0.f};
  for (int c = 0; c < 512; c += 8){
    F8 w = load8f(mw + c);
    #pragma unroll
    for (int i = 0; i < 8; ++i){
      ab += w.v[i]*v1ll[c+i];
      mh[i&3] += w.v[i]*dvl[c+i];
    }
  }
  float* P = PRE + (size_t)b * PRE_STRIDE;
  P[2064 + r] = ab;
  *(float4*)&P[2576 + r*4] = make_float4(mh[0],mh[1],mh[2],mh[3]);
}

// ---------------- convert fp32 -> bf16 (flat) ------------------------------
__global__ __launch_bounds__(256) void kcvt(const float* __restrict__ s,
                                            u16* __restrict__ d, int n8)
{
  int g = blockIdx.x*256 + threadIdx.x;
  if (g >= n8) return;
  F8 v = load8f(s + (size_t)g*8);
  u16 o[8];
  #pragma unroll
  for (int i=0;i<8;++i) o[i] = f2bf(v.v[i]);
  *(uint4*)(d + (size_t)g*8) = *(uint4*)o;
}

// ------- build Wg64 [64][1024] = [g1_w | g1_w] bf16 ------------------------
__global__ __launch_bounds__(256) void kcvt_dup(const float* __restrict__ g1w,
                                                u16* __restrict__ out)
{
  int idx = blockIdx.x*256 + threadIdx.x;      // 65536 total
  int r = idx >> 10, k = idx & 1023;
  out[idx] = f2bf(g1w[r*512 + (k & 511)]);
}

// ---- K1: one pass over x: XYbT[j][0..511]=x bf16, [512..1023]=attn+LN(n0) --
// 64 cols/block, 4-way channel split. Stores in 64B full-line bursts.
__global__ __launch_bounds__(256) void k1_fused(
    const float* __restrict__ x, const float* __restrict__ PRE,
    const float* __restrict__ n0_g, const float* __restrict__ n0_b,
    int j0_global, u16* __restrict__ XYbT)
{
  __shared__ float wd[4][512];
  __shared__ float bs[512];
  __shared__ float Mm[512][4];
  __shared__ float gam[512], bet[512];
  __shared__ float beta4[4];
  __shared__ float part[4][4][64];
  __shared__ float pstat[2][4][64];
  const int tid = threadIdx.x;
  const int cid = tid & 63;
  const int qtr = tid >> 6;
  const int jl = blockIdx.x*64 + cid;
  const int jg = j0_global + jl;
  const int b = jg >> 12, n = jg & 4095;   // 4096 % 64 == 0: no b-straddle
  const float* P = PRE + (size_t)b * PRE_STRIDE;
  for (int i = tid; i < 2048; i += 256) wd[i>>9][i&511] = P[i];
  if (tid < 4) beta4[tid] = P[2048 + tid];
  for (int i = tid; i < 512; i += 256){
    bs[i] = P[2064 + i]; gam[i] = n0_g[i]; bet[i] = n0_b[i];
  }
  for (int i = tid; i < 2048; i += 256) Mm[i>>2][i&3] = P[2576 + i];
  __syncthreads();
  const float* xc = x + (size_t)b*2097152 + n;
  u16* col = XYbT + (size_t)jl*1024;
  const int ibase = qtr*128;
  float l0=0.f, l1=0.f, l2=0.f, l3=0.f;
  for (int i0 = 0; i0 < 128; i0 += 32){
    u16 ob[32];
    #pragma unroll
    for (int m = 0; m < 32; ++m){
      int i = ibase + i0 + m;
      float xv = xc[(size_t)i*4096];
      ob[m] = f2bf(xv);
      l0 += wd[0][i]*xv; l1 += wd[1][i]*xv;
      l2 += wd[2][i]*xv; l3 += wd[3][i]*xv;
    }
    #pragma unroll
    for (int q = 0; q < 4; ++q)            // one full 64B line, back-to-back
      *(uint4*)&col[ibase + i0 + 8*q] = *(uint4*)&ob[8*q];
  }
  part[0][qtr][cid] = l0; part[1][qtr][cid] = l1;
  part[2][qtr][cid] = l2; part[3][qtr][cid] = l3;
  __syncthreads();
  l0 = part[0][0][cid] + part[0][1][cid] + part[0][2][cid] + part[0][3][cid] + beta4[0];
  l1 = part[1][0][cid] + part[1][1][cid] + part[1][2][cid] + part[1][3][cid] + beta4[1];
  l2 = part[2][0][cid] + part[2][1][cid] + part[2][2][cid] + part[2][3][cid] + beta4[2];
  l3 = part[3][0][cid] + part[3][1][cid] + part[3][2][cid] + part[3][3][cid] + beta4[3];
  const float sc = 0.0883883476483184405f;
  float p0 = 1.f/(1.f+expf(-sc*l0));
  float p1 = 1.f/(1.f+expf(-sc*l1));
  float p2 = 1.f/(1.f+expf(-sc*l2));
  float p3 = 1.f/(1.f+expf(-sc*l3));
  float s=0.f, s2=0.f;
  for (int c = ibase; c < ibase + 128; ++c){
    float m = bs[c] + Mm[c][0]*p0 + Mm[c][1]*p1 + Mm[c][2]*p2 + Mm[c][3]*p3;
    s += m; s2 += m*m;
  }
  pstat[0][qtr][cid] = s; pstat[1][qtr][cid] = s2;
  __syncthreads();
  s  = pstat[0][0][cid] + pstat[0][1][cid] + pstat[0][2][cid] + pstat[0][3][cid];
  s2 = pstat[1][0][cid] + pstat[1][1][cid] + pstat[1][2][cid] + pstat[1][3][cid];
  float mean = s*(1.f/512.f);
  float rs = rsqrtf(s2*(1.f/512.f) - mean*mean + 1e-5f);
  for (int c0 = 0; c0 < 128; c0 += 32){
    u16 ob[32];
    #pragma unroll
    for (int m = 0; m < 32; ++m){
      int c = ibase + c0 + m;
      float v = bs[c] + Mm[c][0]*p0 + Mm[c][1]*p1 + Mm[c][2]*p2 + Mm[c][3]*p3;
      ob[m] = f2bf((v - mean)*rs*gam[c] + bet[c]);
    }
    #pragma unroll
    for (int q = 0; q < 4; ++q)            // full 64B line, back-to-back
      *(uint4*)&col[512 + ibase + c0 + 8*q] = *(uint4*)&ob[8*q];
  }
}

// --------- MFMA GEMM: paired K-steps, 4 LDS buffers, T2 swizzle ------------
// Out[C][M] bf16 = act(Wb @ XT^T + bias). Wb [M][K]; XT [C][1024].
// 128x128 tile. Per iteration: compute 2 tiles (32 MFMA) between ONE barrier
// pair; stage the next PAIR after barrier-2 (slot's readers provably done).
// Staging uses 4 running per-lane pointers (+32/tile) -- no per-iter address
// re-materialization (the round-9 VALU pathology). vmcnt(8) drains exactly
// the current pair (16 outstanding steady-state). K multiple of 64, K>=192.
__global__ __launch_bounds__(256) void mfma_gemm_p(
    const u16* __restrict__ Wb, const float* __restrict__ bias,
    const u16* __restrict__ XT, int K, int M,
    u16* __restrict__ Out, int do_gelu, int log2nbi)
{
  __shared__ __align__(16) u16 SH[4][8192];  // per buf: A[128][32] | B[128][32]
  const int tid = threadIdx.x;
  const int lane = tid & 63;
  const int wv = __builtin_amdgcn_readfirstlane(tid >> 6);
  const int id = blockIdx.x;
  const int bi = (id >> 3) & ((1 << log2nbi) - 1);
  const int bj = (id & 7) + 8 * (id >> (3 + log2nbi));
  const int roff = (wv >> 1) * 64;
  const int noff = (wv & 1) * 64;
  const int lm = lane & 15, quad = lane >> 4;
  const int qs = (quad ^ ((lm >> 1) & 3)) * 8;   // swizzled 16B slot (read)

  f32x4 acc[4][4];
  #pragma unroll
  for (int i=0;i<4;++i){
    #pragma unroll
    for (int j=0;j<4;++j) acc[i][j] = (f32x4){0.f,0.f,0.f,0.f};
  }

  // DMA map: lane -> row r16=lane>>2 (16 rows/instr), 16B slot lane&3.
  // Global k-slot pre-swizzled so linear LDS write lands swizzled layout.
  const int r16 = lane >> 2;
  const int kc  = (((lane & 3) ^ ((lane >> 3) & 3))) * 8;
  const u16* pa0 = Wb + (size_t)(bi*128 + wv*32 + r16)*K + kc;
  const u16* pa1 = pa0 + (size_t)16*K;
  const u16* pb0 = XT + (size_t)(bj*128 + wv*32 + r16)*1024 + kc;
  const u16* pb1 = pb0 + 16*1024;
  const int aOff = wv*1024;          // (wv*32)*32 u16
  const int bOff = 4096 + wv*1024;

#define GP_STAGE(base) do { \
    gload_lds16(pa0, (base) + aOff); \
    gload_lds16(pa1, (base) + aOff + 512); \
    gload_lds16(pb0, (base) + bOff); \
    gload_lds16(pb1, (base) + bOff + 512); \
    pa0 += 32; pa1 += 32; pb0 += 32; pb1 += 32; \
  } while(0)

#define GP_COMPUTE(base) do { \
    bfrag av[4], bv[4]; \
    _Pragma("unroll") \
    for (int i=0;i<4;++i) \
      av[i] = *(const bfrag*)&(base)[(roff + 16*i + lm)*32 + qs]; \
    _Pragma("unroll") \
    for (int j=0;j<4;++j) \
      bv[j] = *(const bfrag*)&(base)[4096 + (noff + 16*j + lm)*32 + qs]; \
    __builtin_amdgcn_s_setprio(1); \
    _Pragma("unroll") \
    for (int i=0;i<4;++i){ \
      _Pragma("unroll") \
      for (int j=0;j<4;++j) \
        acc[i][j] = __builtin_amdgcn_mfma_f32_16x16x32_bf16(av[i], bv[j], acc[i][j], 0,0,0); \
    } \
    __builtin_amdgcn_s_setprio(0); \
  } while(0)

  u16* cA = &SH[0][0];
  u16* cB = &SH[1][0];
  u16* nA = &SH[2][0];
  u16* nB = &SH[3][0];
  GP_STAGE(cA); GP_STAGE(cB);        // pair 0
  GP_STAGE(nA); GP_STAGE(nB);        // pair 1
  const int NIT = (K >> 6) - 2;      // compute pairs 0..NIT-1 in loop
  for (int it = 0; it < NIT; ++it){
    asm volatile("s_waitcnt vmcnt(8)" ::: "memory");  // current pair resident
    __builtin_amdgcn_s_barrier();
    __builtin_amdgcn_sched_barrier(0);
    GP_COMPUTE(cA);
    GP_COMPUTE(cB);
    __builtin_amdgcn_sched_barrier(0);
    __builtin_amdgcn_s_barrier();    // all reads of cA/cB done
    __builtin_amdgcn_sched_barrier(0);
    GP_STAGE(cA); GP_STAGE(cB);      // stage pair it+2 into freed slots
    u16* t;
    t = cA; cA = nA; nA = t;
    t = cB; cB = nB; nB = t;
  }
  asm volatile("s_waitcnt vmcnt(8)" ::: "memory");
  __builtin_amdgcn_s_barrier();
  __builtin_amdgcn_sched_barrier(0);
  GP_COMPUTE(cA);
  GP_COMPUTE(cB);
  asm volatile("s_waitcnt vmcnt(0)" ::: "memory");
  __builtin_amdgcn_s_barrier();
  __builtin_amdgcn_sched_barrier(0);
  GP_COMPUTE(nA);
  GP_COMPUTE(nB);
  __syncthreads();
#undef GP_STAGE
#undef GP_COMPUTE

  // single-pass epilogue: all waves write their frags into 128x136 transpose
  u16* Tt = &SH[0][0];                 // 128*136 = 17408 u16 <= 32768
  #pragma unroll
  for (int i=0;i<4;++i){
    float4 bb = *(const float4*)&bias[bi*128 + roff + 16*i + quad*4];
    float b4[4] = {bb.x,bb.y,bb.z,bb.w};
    #pragma unroll
    for (int j=0;j<4;++j){
      int colr = noff + 16*j + lm;
      #pragma unroll
      for (int s2=0;s2<2;++s2){
        float v0 = acc[i][j][2*s2]   + b4[2*s2];
        float v1 = acc[i][j][2*s2+1] + b4[2*s2+1];
        if (do_gelu){ v0 = gelu_f(v0); v1 = gelu_f(v1); }
        unsigned int dw = (unsigned int)f2bf(v0) | ((unsigned int)f2bf(v1) << 16);
        *(unsigned int*)&Tt[colr*136 + roff + 16*i + quad*4 + 2*s2] = dw;
      }
    }
  }
  __syncthreads();
  {
    int c = tid >> 1, q = tid & 1;     // col 0..127, 64-u16 half
    u16* dst = Out + (size_t)(bj*128 + c)*M + bi*128 + q*64;
    const u16* src = &Tt[c*136 + q*64];
    #pragma unroll
    for (int m=0;m<8;++m)
      *(uint4*)(dst + m*8) = *(const uint4*)(src + m*8);
  }
}

// ---- MFMA g1 GEMM + FUSED HEAD (T2 swizzle, round-8 two-barrier loop) -----
__global__ __launch_bounds__(256) void mfma_g64h(
    const u16* __restrict__ Wg, const float* __restrict__ bias,
    const u16* __restrict__ XT,
    const float* __restrict__ gl1_g, const float* __restrict__ gl1_b,
    const float* __restrict__ g2_w, const float* __restrict__ g2_b,
    const float* __restrict__ gl2_g, const float* __restrict__ gl2_b,
    const float* __restrict__ g3_w, const float* __restrict__ g3_b,
    const float* __restrict__ gl3_g, const float* __restrict__ gl3_b,
    const float* __restrict__ g4_w, const float* __restrict__ g4_b, int has_g4b,
    float* __restrict__ Outp, int j0_global)
{
  __shared__ __align__(16) u16 SH[3][6144];  // per buf: A[64][32] | B[128][32]
  const int tid = threadIdx.x;
  const int lane = tid & 63;
  const int wv = __builtin_amdgcn_readfirstlane(tid >> 6);
  const int bj = blockIdx.x;
  const int lm = lane & 15, quad = lane >> 4;
  const int qs = (quad ^ ((lm >> 1) & 3)) * 8;   // swizzled 16B slot (read)

  f32x4 acc[4][2];
  #pragma unroll
  for (int i=0;i<4;++i){
    #pragma unroll
    for (int j=0;j<2;++j) acc[i][j] = (f32x4){0.f,0.f,0.f,0.f};
  }
  const int r16 = lane >> 2;
  const int kc  = (((lane & 3) ^ ((lane >> 3) & 3))) * 8;
  const u16* aG = Wg + (size_t)(wv*16 + r16)*1024 + kc;
  const u16* bG = XT + (size_t)(bj*128 + wv*32 + r16)*1024 + kc;
  const int aOff = wv*512;            // (wv*16)*32
  const int bOff = 2048 + wv*1024;    // B area + (wv*32)*32

#define G64_STAGE(base, kk) do { \
    gload_lds16(aG + (kk),             (base) + aOff); \
    gload_lds16(bG + (kk),             (base) + bOff); \
    gload_lds16(bG + 16*1024 + (kk),   (base) + bOff + 512); \
  } while(0)

#define G64_COMPUTE(base) do { \
    bfrag av[4], bv[2]; \
    _Pragma("unroll") \
    for (int i=0;i<4;++i) \
      av[i] = *(const bfrag*)&(base)[(16*i + lm)*32 + qs]; \
    _Pragma("unroll") \
    for (int j=0;j<2;++j) \
      bv[j] = *(const bfrag*)&(base)[2048 + (wv*32 + 16*j + lm)*32 + qs]; \
    __builtin_amdgcn_s_setprio(1); \
    _Pragma("unroll") \
    for (int i=0;i<4;++i){ \
      _Pragma("unroll") \
      for (int j=0;j<2;++j) \
        acc[i][j] = __builtin_amdgcn_mfma_f32_16x16x32_bf16(av[i], bv[j], acc[i][j], 0,0,0); \
    } \
    __builtin_amdgcn_s_setprio(0); \
  } while(0)

  u16* b0 = &SH[0][0];
  u16* b1 = &SH[1][0];
  u16* b2 = &SH[2][0];
  G64_STAGE(b0, 0);
  G64_STAGE(b1, 32);
  for (int k0 = 0; k0 + 64 < 1024; k0 += 32){
    G64_STAGE(b2, k0 + 64);
    asm volatile("s_waitcnt vmcnt(6)" ::: "memory");
    __builtin_amdgcn_s_barrier();
    __builtin_amdgcn_sched_barrier(0);
    G64_COMPUTE(b0);
    __builtin_amdgcn_sched_barrier(0);
    __builtin_amdgcn_s_barrier();
    u16* t = b0; b0 = b1; b1 = b2; b2 = t;
  }
  asm volatile("s_waitcnt vmcnt(3)" ::: "memory");
  __builtin_amdgcn_s_barrier();
  __builtin_amdgcn_sched_barrier(0);
  G64_COMPUTE(b0);
  asm volatile("s_waitcnt vmcnt(0)" ::: "memory");
  __builtin_amdgcn_s_barrier();
  __builtin_amdgcn_sched_barrier(0);
  G64_COMPUTE(b1);
  __syncthreads();
#undef G64_STAGE
#undef G64_COMPUTE

  // stage raw g1 [128 cols][64 ch] (stride 72) into SH
  u16* Tg = &SH[0][0];                 // 128*72 = 9216 u16 = 18KB
  #pragma unroll
  for (int i=0;i<4;++i){
    float4 bb = *(const float4*)&bias[16*i + quad*4];
    float b4[4] = {bb.x,bb.y,bb.z,bb.w};
    #pragma unroll
    for (int j=0;j<2;++j){
      int col = wv*32 + 16*j + lm;
      #pragma unroll
      for (int s2=0;s2<2;++s2){
        float v0 = acc[i][j][2*s2]   + b4[2*s2];
        float v1 = acc[i][j][2*s2+1] + b4[2*s2+1];
        unsigned int dw = (unsigned int)f2bf(v0) | ((unsigned int)f2bf(v1) << 16);
        *(unsigned int*)&Tg[col*72 + 16*i + quad*4 + 2*s2] = dw;
      }
    }
  }
  // stage head weights into LDS above Tg (byte off 18432; 1281 floats = 5KB)
  float* HW = (float*)(&SH[0][0] + 9216);
  if (tid < 64){ HW[tid] = gl1_g[tid]; HW[64+tid] = gl1_b[tid]; }
  for (int i = tid; i < 1024; i += 256) HW[128+i] = g2_w[i];
  if (tid < 16){ HW[1152+tid]=g2_b[tid]; HW[1168+tid]=gl2_g[tid]; HW[1184+tid]=gl2_b[tid]; }
  if (tid >= 64 && tid < 128) HW[1200 + tid-64] = g3_w[tid-64];
  if (tid >= 128 && tid < 132){
    int q = tid - 128;
    HW[1264+q]=g3_b[q]; HW[1268+q]=gl3_g[q]; HW[1272+q]=gl3_b[q];
    HW[1276+q] = g4_w[q] - g4_w[4+q];
  }
  if (tid == 132) HW[1280] = has_g4b ? (g4_b[0] - g4_b[1]) : 0.f;
  __syncthreads();

  if (tid < 128){
    const u16* gc = &Tg[tid*72];
    float a1[64]; float s=0.f;
    #pragma unroll
    for (int c0=0;c0<64;c0+=8){
      uint4 w = *(const uint4*)(gc + c0);
      const u16* wp = (const u16*)&w;
      #pragma unroll
      for (int m=0;m<8;++m){ a1[c0+m] = bf2f(wp[m]); s += a1[c0+m]; }
    }
    float m = s*(1.f/64.f); float s2=0.f;
    #pragma unroll
    for (int c=0;c<64;++c){ float d=a1[c]-m; s2+=d*d; }
    float rs = rsqrtf(s2*(1.f/64.f)+1e-5f);
    #pragma unroll
    for (int c=0;c<64;++c) a1[c] = gelu_f((a1[c]-m)*rs*HW[c]+HW[64+c]);

    float a2[16]; s=0.f;
    #pragma unroll
    for (int i=0;i<16;++i){
      float acc2 = HW[1152+i];
      #pragma unroll
      for (int o=0;o<64;++o) acc2 += HW[128 + i*64 + o]*a1[o];
      a2[i]=acc2; s+=acc2;
    }
    m = s*(1.f/16.f); s2=0.f;
    #pragma unroll
    for (int i=0;i<16;++i){ float d=a2[i]-m; s2+=d*d; }
    rs = rsqrtf(s2*(1.f/16.f)+1e-5f);
    float a2g[16];
    #pragma unroll
    for (int i=0;i<16;++i) a2g[i] = gelu_f((a2[i]-m)*rs*HW[1168+i]+HW[1184+i]);

    float a3[4]; s=0.f;
    #pragma unroll
    for (int i=0;i<4;++i){
      float acc3 = HW[1264+i];
      #pragma unroll
      for (int o=0;o<16;++o) acc3 += HW[1200 + i*16 + o]*a2g[o];
      a3[i]=acc3; s+=acc3;
    }
    m = s*0.25f; s2=0.f;
    #pragma unroll
    for (int i=0;i<4;++i){ float d=a3[i]-m; s2+=d*d; }
    rs = rsqrtf(s2*0.25f+1e-5f);
    float z = HW[1280];
    #pragma unroll
    for (int i=0;i<4;++i) z += HW[1276+i]*gelu_f((a3[i]-m)*rs*HW[1268+i]+HW[1272+i]);
    Outp[j0_global + bj*128 + tid] = 1.f/(1.f+expf(-z));
  }
}

// ---- LN over 512 ch, wave-per-column; bf16 in, bf16 out into XYbT y-half --
__global__ __launch_bounds__(256) void k_lnT(
    const u16* __restrict__ t2T,
    const float* __restrict__ gamma, const float* __restrict__ beta,
    u16* __restrict__ XYbT)
{
  __shared__ float gam[512], bet[512];
  const int tid = threadIdx.x;
  for (int c = tid; c < 512; c += 256){ gam[c]=gamma[c]; bet[c]=beta[c]; }
  __syncthreads();
  const int lane = tid & 63, wv = tid >> 6;
  const int j = blockIdx.x*4 + wv;
  uint4 w = *(const uint4*)(t2T + (size_t)j*512 + lane*8);
  const u16* wp = (const u16*)&w;
  float vv[8];
  #pragma unroll
  for (int m=0;m<8;++m) vv[m] = bf2f(wp[m]);
  float s = 0.f, s2 = 0.f;
  #pragma unroll
  for (int m=0;m<8;++m){ s += vv[m]; s2 += vv[m]*vv[m]; }
  #pragma unroll
  for (int off = 32; off; off >>= 1){
    s  += __shfl_xor(s,  off, 64);
    s2 += __shfl_xor(s2, off, 64);
  }
  float mean = s*(1.f/512.f);
  float rs = rsqrtf(s2*(1.f/512.f) - mean*mean + 1e-5f);
  u16 ob[8];
  #pragma unroll
  for (int m=0;m<8;++m){
    int c = lane*8 + m;
    ob[m] = f2bf((vv[m]-mean)*rs*gam[c] + bet[c]);
  }
  *(uint4*)&XYbT[(size_t)j*1024 + 512 + lane*8] = *(uint4*)ob;
}

extern "C" void kernel_launch(void* const* d_in, const int* in_sizes, int n_in,
                              void* d_out, int out_size, void* d_ws, size_t ws_size,
                              hipStream_t stream)
{
  const float* gtok  = (const float*)d_in[0];
  const float* x     = (const float*)d_in[1];
  const float* ws1_w = (const float*)d_in[2];
  const float* ws1_b = (const float*)d_in[3];
  const float* ws2_w = (const float*)d_in[4];
  const float* ws2_b = (const float*)d_in[5];
  const float* wc1_w = (const float*)d_in[6];
  const float* wc1_b = (const float*)d_in[7];
  const float* wc2_w = (const float*)d_in[8];
  const float* wc2_b = (const float*)d_in[9];
  const float* q_w   = (const float*)d_in[10];
  const float* q_b   = (const float*)d_in[11];
  const float* k_w   = (const float*)d_in[12];
  const float* v_w   = (const float*)d_in[14];
  const float* v_b   = (const float*)d_in[15];
  const float* merge_w = (const float*)d_in[16];
  const float* merge_b = (const float*)d_in[17];
  const float* m1_w  = (const float*)d_in[18];
  const float* m1_b  = (const float*)d_in[19];
  const float* m2_w  = (const float*)d_in[20];
  const float* m2_b  = (const float*)d_in[21];
  const float* n0_g  = (const float*)d_in[22];
  const float* n0_b  = (const float*)d_in[23];
  const float* n1_g  = (const float*)d_in[24];
  const float* n1_b  = (const float*)d_in[25];
  const float* g1_w  = (const float*)d_in[26];
  const float* g1_b  = (const float*)d_in[27];
  const float* gl1_g = (const float*)d_in[28];
  const float* gl1_b = (const float*)d_in[29];
  const float* g2_w  = (const float*)d_in[30];
  const float* g2_b  = (const float*)d_in[31];
  const float* gl2_g = (const float*)d_in[32];
  const float* gl2_b = (const float*)d_in[33];
  const float* g3_w  = (const float*)d_in[34];
  const float* g3_b  = (const float*)d_in[35];
  const float* gl3_g = (const float*)d_in[36];
  const float* gl3_b = (const float*)d_in[37];
  const float* g4_w  = (const float*)d_in[38];
  const float* g4_b  = (n_in > 39) ? (const float*)d_in[39] : nullptr;

  const int TOT = 65536;
  const size_t PRE_BYTES = (size_t)16 * PRE_STRIDE * 4;
  const size_t GT1_B = 65536, HID_B = 262144, GT2_B = 65536;
  const size_t DK_B = 32768, DV_B = 32768, V1L_B = 32768;
  const size_t WB1_B = (size_t)1024*1024*2;
  const size_t WB2_B = (size_t)512*1024*2;
  const size_t WG_B  = (size_t)64*1024*2;
  const size_t FIXED = PRE_BYTES + GT1_B + HID_B + GT2_B + DK_B + DV_B + V1L_B
                     + WB1_B + WB2_B + WG_B;
  // per-chunk: XYbT 2048C + T1bT 2048C + T2bT 1024C = 5120C bytes
  int C = 65536;
  while (C > 4096 && FIXED + (size_t)5120*C > ws_size) C >>= 1;
  const int nch = TOT / C;

  char* wsb = (char*)d_ws;
  size_t off = 0;
  float* PRE = (float*)(wsb + off); off += PRE_BYTES;
  float* GT1 = (float*)(wsb + off); off += GT1_B;
  float* HID = (float*)(wsb + off); off += HID_B;
  float* GT2 = (float*)(wsb + off); off += GT2_B;
  float* DK  = (float*)(wsb + off); off += DK_B;
  float* DV  = (float*)(wsb + off); off += DV_B;
  float* V1L = (float*)(wsb + off); off += V1L_B;
  u16* Wb1   = (u16*)(wsb + off);   off += WB1_B;
  u16* Wb2   = (u16*)(wsb + off);   off += WB2_B;
  u16* Wg    = (u16*)(wsb + off);   off += WG_B;
  u16* XYbT  = (u16*)(wsb + off);   off += (size_t)2048*C;  // [C][1024] bf16
  u16* T1bT  = (u16*)(wsb + off);   off += (size_t)2048*C;  // [C][1024] bf16
  u16* T2bT  = (u16*)(wsb + off);   off += (size_t)1024*C;  // [C][512] bf16

  dim3 blk(256);
  hipLaunchKernelGGL(kcvt, dim3(512), blk, 0, stream, m1_w, Wb1, 1024*1024/8);
  hipLaunchKernelGGL(kcvt, dim3(256), blk, 0, stream, m2_w, Wb2, 512*1024/8);
  hipLaunchKernelGGL(kcvt_dup, dim3(256), blk, 0, stream, g1_w, Wg);
  hipLaunchKernelGGL(k0a_mlps, dim3(16,2), blk, 0, stream,
      gtok, ws1_w, ws1_b, ws2_w, ws2_b, GT1);
  hipLaunchKernelGGL(k0b_fc1, dim3(16,8), blk, 0, stream, GT1, wc1_w, wc1_b, HID);
  hipLaunchKernelGGL(k0c_fc2, dim3(16,2), blk, 0, stream, GT1, HID, wc2_w, wc2_b, GT2);
  hipLaunchKernelGGL(k0d_kv,  dim3(16,2), blk, 0, stream, GT2, k_w, v_w, v_b, DK, DV, V1L);
  hipLaunchKernelGGL(k0e_qpre, dim3(16,2), blk, 0, stream, DK, q_w, q_b, PRE);
  hipLaunchKernelGGL(k0f_mpre, dim3(16,2), blk, 0, stream, DV, V1L, merge_w, merge_b, PRE);

  for (int ch = 0; ch < nch; ++ch){
    const int j0 = ch * C;
    // x->bf16 + attn + merge + LN(n0) in one pass over x -> XYbT
    hipLaunchKernelGGL(k1_fused, dim3(C/64), blk, 0, stream,
        x, PRE, n0_g, n0_b, j0, XYbT);
    // t1 = gelu(m1 @ XY + b) -> T1bT  (M=1024, nbi=8)
    hipLaunchKernelGGL(mfma_gemm_p, dim3(8*(C/128)), blk, 0, stream,
        Wb1, m1_b, XYbT, 1024, 1024, T1bT, 1, 3);
    // t2 = m2 @ t1 + b -> T2bT       (M=512, nbi=4)
    hipLaunchKernelGGL(mfma_gemm_p, dim3(4*(C/128)), blk, 0, stream,
        Wb2, m2_b, T1bT, 1024, 512, T2bT, 0, 2);
    // LN(t2; n1) -> bf16, overwrite y-half of XYbT (x-half stays = x bf16)
    hipLaunchKernelGGL(k_lnT, dim3(C/4), blk, 0, stream, T2bT, n1_g, n1_b, XYbT);
    // g1 GEMM + fused head -> d_out directly
    hipLaunchKernelGGL(mfma_g64h, dim3(C/128), blk, 0, stream,
        Wg, g1_b, XYbT,
        gl1_g, gl1_b, g2_w, g2_b, gl2_g, gl2_b,
        g3_w, g3_b, gl3_g, gl3_b,
        g4_w, g4_b ? g4_b : g4_w, g4_b ? 1 : 0, (float*)d_out, j0);
  }
}

// Round 12
// 912.877 us; speedup vs baseline: 1.0044x; 1.0044x over previous
//
#include <hip/hip_runtime.h>
#include <math.h>

typedef unsigned short u16;
typedef unsigned int u32;
typedef __attribute__((ext_vector_type(8))) short bfrag;   // 8 bf16 (4 VGPRs)
typedef __attribute__((ext_vector_type(4))) float f32x4;

// fast gelu: erf(z) via Abramowitz-Stegun 7.1.26 (|eps|<=1.5e-7), z = x/sqrt(2)
__device__ __forceinline__ float gelu_f(float x){
  float z = fabsf(x) * 0.70710678118654752440f;
  float t = __builtin_amdgcn_rcpf(1.0f + 0.3275911f*z);
  float p = t*(0.254829592f + t*(-0.284496736f + t*(1.421413741f
            + t*(-1.453152027f + t*1.061405429f))));
  float e = __expf(-z*z);
  float er = copysignf(1.0f - p*e, x);
  return 0.5f * x * (1.0f + er);
}
__device__ __forceinline__ u16 f2bf(float f){
  union { float f; unsigned int i; } c; c.f = f;
  unsigned int i = c.i;
  return (u16)((i + 0x7FFFu + ((i >> 16) & 1u)) >> 16);
}
__device__ __forceinline__ float bf2f(u16 u){
  union { unsigned int i; float f; } c; c.i = ((unsigned int)u) << 16; return c.f;
}

// async global->LDS DMA, 16B per lane. LDS dest = wave-uniform base + lane*16B.
__device__ __forceinline__ void gload_lds16(const u16* g, u16* l){
  __builtin_amdgcn_global_load_lds(
      (const __attribute__((address_space(1))) u32*)(g),
      (__attribute__((address_space(3))) u32*)(l),
      16, 0, 0);
}

struct F8 { float v[8]; };
__device__ __forceinline__ F8 load8f(const float* p){
  float4 a = *(const float4*)p; float4 b = *(const float4*)(p + 4);
  F8 r; r.v[0]=a.x; r.v[1]=a.y; r.v[2]=a.z; r.v[3]=a.w;
  r.v[4]=b.x; r.v[5]=b.y; r.v[6]=b.z; r.v[7]=b.w; return r;
}

#define PRE_STRIDE 4624

// ============ k0 phase A: mlp_s (2->256->2) + residual -> GT1 ==============
__global__ __launch_bounds__(256) void k0a_mlps(
    const float* __restrict__ gtok,
    const float* __restrict__ ws1_w, const float* __restrict__ ws1_b,
    const float* __restrict__ ws2_w, const float* __restrict__ ws2_b,
    float* __restrict__ GT1)
{
  __shared__ float sw1[256][2]; __shared__ float sb1[256];
  __shared__ float sw2[2][256];
  const int b = blockIdx.x;
  const int t = threadIdx.x;
  sw1[t][0] = ws1_w[2*t]; sw1[t][1] = ws1_w[2*t+1];
  sb1[t] = ws1_b[t];
  sw2[0][t] = ws2_w[t]; sw2[1][t] = ws2_w[256+t];
  __syncthreads();
  const int j = blockIdx.y*256 + t;
  const float a0 = gtok[b*1024 + 2*j], a1 = gtok[b*1024 + 2*j + 1];
  float s0 = ws2_b[0], s1 = ws2_b[1];
  #pragma unroll 4
  for (int o = 0; o < 256; ++o){
    float h = gelu_f(sw1[o][0]*a0 + sw1[o][1]*a1 + sb1[o]);
    s0 += sw2[0][o]*h; s1 += sw2[1][o]*h;
  }
  GT1[b*1024 + 2*j]     = a0 + s0;
  GT1[b*1024 + 2*j + 1] = a1 + s1;
}

// ============ k0 phase B: fc1 of mlp_c (512->2048) -> HID ==================
__global__ __launch_bounds__(256) void k0b_fc1(
    const float* __restrict__ GT1,
    const float* __restrict__ wc1_w, const float* __restrict__ wc1_b,
    float* __restrict__ HID)
{
  __shared__ float g[1024];
  const int b = blockIdx.x;
  const int t = threadIdx.x;
  for (int i = t; i < 1024; i += 256) g[i] = GT1[b*1024 + i];
  __syncthreads();
  const int o = blockIdx.y*256 + t;
  const float* wr = wc1_w + (size_t)o*512;
  float acc0 = wc1_b[o], acc1 = acc0;
  for (int d = 0; d < 512; d += 8){
    F8 w = load8f(wr + d);
    #pragma unroll
    for (int i = 0; i < 8; ++i){
      acc0 += w.v[i]*g[(d+i)*2];
      acc1 += w.v[i]*g[(d+i)*2+1];
    }
  }
  HID[b*4096 + o]        = gelu_f(acc0);
  HID[b*4096 + 2048 + o] = gelu_f(acc1);
}

// ============ k0 phase C: fc2 of mlp_c (2048->512) + residual -> GT2 =======
__global__ __launch_bounds__(256) void k0c_fc2(
    const float* __restrict__ GT1, const float* __restrict__ HID,
    const float* __restrict__ wc2_w, const float* __restrict__ wc2_b,
    float* __restrict__ GT2)
{
  __shared__ float h0[2048], h1[2048];
  const int b = blockIdx.x;
  const int t = threadIdx.x;
  for (int i = t; i < 2048; i += 256){
    h0[i] = HID[b*4096 + i]; h1[i] = HID[b*4096 + 2048 + i];
  }
  __syncthreads();
  const int d = blockIdx.y*256 + t;
  const float* wr = wc2_w + (size_t)d*2048;
  float acc0 = wc2_b[d], acc1 = acc0;
  for (int o = 0; o < 2048; o += 8){
    F8 w = load8f(wr + o);
    #pragma unroll
    for (int i = 0; i < 8; ++i){
      acc0 += w.v[i]*h0[o+i];
      acc1 += w.v[i]*h1[o+i];
    }
  }
  GT2[b*1024 + 2*d]     = GT1[b*1024 + 2*d]     + acc0;
  GT2[b*1024 + 2*d + 1] = GT1[b*1024 + 2*d + 1] + acc1;
}

// ============ k0 phase D: k,v -> dk, dv, v1l ================================
__global__ __launch_bounds__(256) void k0d_kv(
    const float* __restrict__ GT2,
    const float* __restrict__ k_w,
    const float* __restrict__ v_w, const float* __restrict__ v_b,
    float* __restrict__ DK, float* __restrict__ DV, float* __restrict__ V1L)
{
  __shared__ float g[1024];
  const int b = blockIdx.x;
  const int t = threadIdx.x;
  for (int i = t; i < 1024; i += 256) g[i] = GT2[b*1024 + i];
  __syncthreads();
  const int c = blockIdx.y*256 + t;
  const float* kr = k_w + (size_t)c*512;
  const float* vr = v_w + (size_t)c*512;
  float k0a=0.f,k1a=0.f,v0a=0.f,v1a=0.f;
  for (int d = 0; d < 512; d += 8){
    F8 kw = load8f(kr + d); F8 vw = load8f(vr + d);
    #pragma unroll
    for (int i = 0; i < 8; ++i){
      float g0 = g[(d+i)*2], g1 = g[(d+i)*2+1];
      k0a += kw.v[i]*g0; k1a += kw.v[i]*g1;
      v0a += vw.v[i]*g0; v1a += vw.v[i]*g1;
    }
  }
  DK[b*512 + c]  = k0a - k1a;
  DV[b*512 + c]  = v0a - v1a;
  V1L[b*512 + c] = v1a + v_b[c];
}

// ============ k0 phase E: wdiff + beta4 -> PRE ==============================
__global__ __launch_bounds__(256) void k0e_qpre(
    const float* __restrict__ DK,
    const float* __restrict__ q_w, const float* __restrict__ q_b,
    float* __restrict__ PRE)
{
  __shared__ float dkl[512];
  const int b = blockIdx.x;
  const int t = threadIdx.x;
  for (int i = t; i < 512; i += 256) dkl[i] = DK[b*512 + i];
  __syncthreads();
  const int i = blockIdx.y*256 + t;
  float w0=0.f,w1=0.f,w2=0.f,w3=0.f;
  for (int c = 0; c < 512; c += 4){
    w0 += dkl[c]  *q_w[(size_t)(c)  *512 + i];
    w1 += dkl[c+1]*q_w[(size_t)(c+1)*512 + i];
    w2 += dkl[c+2]*q_w[(size_t)(c+2)*512 + i];
    w3 += dkl[c+3]*q_w[(size_t)(c+3)*512 + i];
  }
  float* P = PRE + (size_t)b * PRE_STRIDE;
  P[0*512+i]=w0; P[1*512+i]=w1; P[2*512+i]=w2; P[3*512+i]=w3;
  if (blockIdx.y == 0 && t < 4){
    float bsum = 0.f;
    for (int c = t; c < 512; c += 4) bsum += dkl[c]*q_b[c];
    P[2048 + t] = bsum;
  }
}

// ============ k0 phase F: base + M -> PRE ===================================
__global__ __launch_bounds__(256) void k0f_mpre(
    const float* __restrict__ DV, const float* __restrict__ V1L,
    const float* __restrict__ merge_w, const float* __restrict__ merge_b,
    float* __restrict__ PRE)
{
  __shared__ float dvl[512], v1ll[512];
  const int b = blockIdx.x;
  const int t = threadIdx.x;
  for (int i = t; i < 512; i += 256){
    dvl[i] = DV[b*512 + i]; v1ll[i] = V1L[b*512 + i];
  }
  __syncthreads();
  const int r = blockIdx.y*256 + t;
  const float* mw = merge_w + (size_t)r*512;
  float ab = merge_b[r];
  float mh[4] = {0.f,0.f,0.f,0.f};
  for (int c = 0; c < 512; c += 8){
    F8 w = load8f(mw + c);
    #pragma unroll
    for (int i = 0; i < 8; ++i){
      ab += w.v[i]*v1ll[c+i];
      mh[i&3] += w.v[i]*dvl[c+i];
    }
  }
  float* P = PRE + (size_t)b * PRE_STRIDE;
  P[2064 + r] = ab;
  *(float4*)&P[2576 + r*4] = make_float4(mh[0],mh[1],mh[2],mh[3]);
}

// ---------------- convert fp32 -> bf16 (flat) ------------------------------
__global__ __launch_bounds__(256) void kcvt(const float* __restrict__ s,
                                            u16* __restrict__ d, int n8)
{
  int g = blockIdx.x*256 + threadIdx.x;
  if (g >= n8) return;
  F8 v = load8f(s + (size_t)g*8);
  u16 o[8];
  #pragma unroll
  for (int i=0;i<8;++i) o[i] = f2bf(v.v[i]);
  *(uint4*)(d + (size_t)g*8) = *(uint4*)o;
}

// ------- build Wg64 [64][1024] = [g1_w | g1_w] bf16 ------------------------
__global__ __launch_bounds__(256) void kcvt_dup(const float* __restrict__ g1w,
                                                u16* __restrict__ out)
{
  int idx = blockIdx.x*256 + threadIdx.x;      // 65536 total
  int r = idx >> 10, k = idx & 1023;
  out[idx] = f2bf(g1w[r*512 + (k & 511)]);
}

// ---- K1: one pass over x: XYbT[j][0..511]=x bf16, [512..1023]=attn+LN(n0) --
// 64 cols/block, 4-way channel split. Stores in 64B full-line bursts.
__global__ __launch_bounds__(256) void k1_fused(
    const float* __restrict__ x, const float* __restrict__ PRE,
    const float* __restrict__ n0_g, const float* __restrict__ n0_b,
    int j0_global, u16* __restrict__ XYbT)
{
  __shared__ float wd[4][512];
  __shared__ float bs[512];
  __shared__ float Mm[512][4];
  __shared__ float gam[512], bet[512];
  __shared__ float beta4[4];
  __shared__ float part[4][4][64];
  __shared__ float pstat[2][4][64];
  const int tid = threadIdx.x;
  const int cid = tid & 63;
  const int qtr = tid >> 6;
  const int jl = blockIdx.x*64 + cid;
  const int jg = j0_global + jl;
  const int b = jg >> 12, n = jg & 4095;   // 4096 % 64 == 0: no b-straddle
  const float* P = PRE + (size_t)b * PRE_STRIDE;
  for (int i = tid; i < 2048; i += 256) wd[i>>9][i&511] = P[i];
  if (tid < 4) beta4[tid] = P[2048 + tid];
  for (int i = tid; i < 512; i += 256){
    bs[i] = P[2064 + i]; gam[i] = n0_g[i]; bet[i] = n0_b[i];
  }
  for (int i = tid; i < 2048; i += 256) Mm[i>>2][i&3] = P[2576 + i];
  __syncthreads();
  const float* xc = x + (size_t)b*2097152 + n;
  u16* col = XYbT + (size_t)jl*1024;
  const int ibase = qtr*128;
  float l0=0.f, l1=0.f, l2=0.f, l3=0.f;
  for (int i0 = 0; i0 < 128; i0 += 32){
    u16 ob[32];
    #pragma unroll
    for (int m = 0; m < 32; ++m){
      int i = ibase + i0 + m;
      float xv = xc[(size_t)i*4096];
      ob[m] = f2bf(xv);
      l0 += wd[0][i]*xv; l1 += wd[1][i]*xv;
      l2 += wd[2][i]*xv; l3 += wd[3][i]*xv;
    }
    #pragma unroll
    for (int q = 0; q < 4; ++q)            // one full 64B line, back-to-back
      *(uint4*)&col[ibase + i0 + 8*q] = *(uint4*)&ob[8*q];
  }
  part[0][qtr][cid] = l0; part[1][qtr][cid] = l1;
  part[2][qtr][cid] = l2; part[3][qtr][cid] = l3;
  __syncthreads();
  l0 = part[0][0][cid] + part[0][1][cid] + part[0][2][cid] + part[0][3][cid] + beta4[0];
  l1 = part[1][0][cid] + part[1][1][cid] + part[1][2][cid] + part[1][3][cid] + beta4[1];
  l2 = part[2][0][cid] + part[2][1][cid] + part[2][2][cid] + part[2][3][cid] + beta4[2];
  l3 = part[3][0][cid] + part[3][1][cid] + part[3][2][cid] + part[3][3][cid] + beta4[3];
  const float sc = 0.0883883476483184405f;
  float p0 = 1.f/(1.f+expf(-sc*l0));
  float p1 = 1.f/(1.f+expf(-sc*l1));
  float p2 = 1.f/(1.f+expf(-sc*l2));
  float p3 = 1.f/(1.f+expf(-sc*l3));
  float s=0.f, s2=0.f;
  for (int c = ibase; c < ibase + 128; ++c){
    float m = bs[c] + Mm[c][0]*p0 + Mm[c][1]*p1 + Mm[c][2]*p2 + Mm[c][3]*p3;
    s += m; s2 += m*m;
  }
  pstat[0][qtr][cid] = s; pstat[1][qtr][cid] = s2;
  __syncthreads();
  s  = pstat[0][0][cid] + pstat[0][1][cid] + pstat[0][2][cid] + pstat[0][3][cid];
  s2 = pstat[1][0][cid] + pstat[1][1][cid] + pstat[1][2][cid] + pstat[1][3][cid];
  float mean = s*(1.f/512.f);
  float rs = rsqrtf(s2*(1.f/512.f) - mean*mean + 1e-5f);
  for (int c0 = 0; c0 < 128; c0 += 32){
    u16 ob[32];
    #pragma unroll
    for (int m = 0; m < 32; ++m){
      int c = ibase + c0 + m;
      float v = bs[c] + Mm[c][0]*p0 + Mm[c][1]*p1 + Mm[c][2]*p2 + Mm[c][3]*p3;
      ob[m] = f2bf((v - mean)*rs*gam[c] + bet[c]);
    }
    #pragma unroll
    for (int q = 0; q < 4; ++q)            // full 64B line, back-to-back
      *(uint4*)&col[512 + ibase + c0 + 8*q] = *(uint4*)&ob[8*q];
  }
}

// --------- MFMA GEMM: gload_lds DMA, depth-2 pipeline, T2 LDS swizzle ------
// Round-10 verified structure (best: m1=198us): 3 buffers, two-barrier loop,
// single-pass 128x136 epilogue. This round: setprio REMOVED (T5 is null-to-
// negative on lockstep barrier-synced GEMMs per m190; it was never isolated).
__global__ __launch_bounds__(256) void mfma_gemm_p(
    const u16* __restrict__ Wb, const float* __restrict__ bias,
    const u16* __restrict__ XT, int K, int M,
    u16* __restrict__ Out, int do_gelu, int log2nbi)
{
  __shared__ __align__(16) u16 SH[3][8192];  // per buf: A[128][32] | B[128][32]
  const int tid = threadIdx.x;
  const int lane = tid & 63;
  const int wv = __builtin_amdgcn_readfirstlane(tid >> 6);
  const int id = blockIdx.x;
  const int bi = (id >> 3) & ((1 << log2nbi) - 1);
  const int bj = (id & 7) + 8 * (id >> (3 + log2nbi));
  const int roff = (wv >> 1) * 64;
  const int noff = (wv & 1) * 64;
  const int lm = lane & 15, quad = lane >> 4;
  const int qs = (quad ^ ((lm >> 1) & 3)) * 8;   // swizzled 16B slot (read)

  f32x4 acc[4][4];
  #pragma unroll
  for (int i=0;i<4;++i){
    #pragma unroll
    for (int j=0;j<4;++j) acc[i][j] = (f32x4){0.f,0.f,0.f,0.f};
  }

  // DMA map: lane -> row r16=lane>>2 (16 rows/instr), 16B slot lane&3.
  // Global k-slot pre-swizzled so linear LDS write lands swizzled layout.
  const int r16 = lane >> 2;
  const int kc  = (((lane & 3) ^ ((lane >> 3) & 3))) * 8;
  const u16* aG = Wb + (size_t)(bi*128 + wv*32 + r16)*K + kc;
  const u16* bG = XT + (size_t)(bj*128 + wv*32 + r16)*1024 + kc;
  const int aOff = wv*1024;          // (wv*32)*32 u16
  const int bOff = 4096 + wv*1024;

#define GP_STAGE(base, kk) do { \
    gload_lds16(aG + (kk),                 (base) + aOff); \
    gload_lds16(aG + (size_t)16*K + (kk),  (base) + aOff + 512); \
    gload_lds16(bG + (kk),                 (base) + bOff); \
    gload_lds16(bG + 16*1024 + (kk),       (base) + bOff + 512); \
  } while(0)

#define GP_COMPUTE(base) do { \
    bfrag av[4], bv[4]; \
    _Pragma("unroll") \
    for (int i=0;i<4;++i) \
      av[i] = *(const bfrag*)&(base)[(roff + 16*i + lm)*32 + qs]; \
    _Pragma("unroll") \
    for (int j=0;j<4;++j) \
      bv[j] = *(const bfrag*)&(base)[4096 + (noff + 16*j + lm)*32 + qs]; \
    _Pragma("unroll") \
    for (int i=0;i<4;++i){ \
      _Pragma("unroll") \
      for (int j=0;j<4;++j) \
        acc[i][j] = __builtin_amdgcn_mfma_f32_16x16x32_bf16(av[i], bv[j], acc[i][j], 0,0,0); \
    } \
  } while(0)

  u16* b0 = &SH[0][0];
  u16* b1 = &SH[1][0];
  u16* b2 = &SH[2][0];
  GP_STAGE(b0, 0);
  GP_STAGE(b1, 32);
  for (int k0 = 0; k0 + 64 < K; k0 += 32){
    GP_STAGE(b2, k0 + 64);                       // prefetch 2 tiles ahead
    asm volatile("s_waitcnt vmcnt(8)" ::: "memory");  // tile k0 resident
    __builtin_amdgcn_s_barrier();
    __builtin_amdgcn_sched_barrier(0);
    GP_COMPUTE(b0);
    __builtin_amdgcn_sched_barrier(0);
    __builtin_amdgcn_s_barrier();                // reads done before overwrite
    u16* t = b0; b0 = b1; b1 = b2; b2 = t;
  }
  asm volatile("s_waitcnt vmcnt(4)" ::: "memory");
  __builtin_amdgcn_s_barrier();
  __builtin_amdgcn_sched_barrier(0);
  GP_COMPUTE(b0);
  asm volatile("s_waitcnt vmcnt(0)" ::: "memory");
  __builtin_amdgcn_s_barrier();
  __builtin_amdgcn_sched_barrier(0);
  GP_COMPUTE(b1);
  __syncthreads();
#undef GP_STAGE
#undef GP_COMPUTE

  // single-pass epilogue: all waves write their frags into 128x136 transpose
  u16* Tt = &SH[0][0];                 // 128*136 = 17408 u16 <= 24576
  #pragma unroll
  for (int i=0;i<4;++i){
    float4 bb = *(const float4*)&bias[bi*128 + roff + 16*i + quad*4];
    float b4[4] = {bb.x,bb.y,bb.z,bb.w};
    #pragma unroll
    for (int j=0;j<4;++j){
      int colr = noff + 16*j + lm;
      #pragma unroll
      for (int s2=0;s2<2;++s2){
        float v0 = acc[i][j][2*s2]   + b4[2*s2];
        float v1 = acc[i][j][2*s2+1] + b4[2*s2+1];
        if (do_gelu){ v0 = gelu_f(v0); v1 = gelu_f(v1); }
        unsigned int dw = (unsigned int)f2bf(v0) | ((unsigned int)f2bf(v1) << 16);
        *(unsigned int*)&Tt[colr*136 + roff + 16*i + quad*4 + 2*s2] = dw;
      }
    }
  }
  __syncthreads();
  {
    int c = tid >> 1, q = tid & 1;     // col 0..127, 64-u16 half
    u16* dst = Out + (size_t)(bj*128 + c)*M + bi*128 + q*64;
    const u16* src = &Tt[c*136 + q*64];
    #pragma unroll
    for (int m=0;m<8;++m)
      *(uint4*)(dst + m*8) = *(const uint4*)(src + m*8);
  }
}

// ---- MFMA g1 GEMM + FUSED HEAD (T2 swizzle, round-10 loop, no setprio) ----
__global__ __launch_bounds__(256) void mfma_g64h(
    const u16* __restrict__ Wg, const float* __restrict__ bias,
    const u16* __restrict__ XT,
    const float* __restrict__ gl1_g, const float* __restrict__ gl1_b,
    const float* __restrict__ g2_w, const float* __restrict__ g2_b,
    const float* __restrict__ gl2_g, const float* __restrict__ gl2_b,
    const float* __restrict__ g3_w, const float* __restrict__ g3_b,
    const float* __restrict__ gl3_g, const float* __restrict__ gl3_b,
    const float* __restrict__ g4_w, const float* __restrict__ g4_b, int has_g4b,
    float* __restrict__ Outp, int j0_global)
{
  __shared__ __align__(16) u16 SH[3][6144];  // per buf: A[64][32] | B[128][32]
  const int tid = threadIdx.x;
  const int lane = tid & 63;
  const int wv = __builtin_amdgcn_readfirstlane(tid >> 6);
  const int bj = blockIdx.x;
  const int lm = lane & 15, quad = lane >> 4;
  const int qs = (quad ^ ((lm >> 1) & 3)) * 8;   // swizzled 16B slot (read)

  f32x4 acc[4][2];
  #pragma unroll
  for (int i=0;i<4;++i){
    #pragma unroll
    for (int j=0;j<2;++j) acc[i][j] = (f32x4){0.f,0.f,0.f,0.f};
  }
  const int r16 = lane >> 2;
  const int kc  = (((lane & 3) ^ ((lane >> 3) & 3))) * 8;
  const u16* aG = Wg + (size_t)(wv*16 + r16)*1024 + kc;
  const u16* bG = XT + (size_t)(bj*128 + wv*32 + r16)*1024 + kc;
  const int aOff = wv*512;            // (wv*16)*32
  const int bOff = 2048 + wv*1024;    // B area + (wv*32)*32

#define G64_STAGE(base, kk) do { \
    gload_lds16(aG + (kk),             (base) + aOff); \
    gload_lds16(bG + (kk),             (base) + bOff); \
    gload_lds16(bG + 16*1024 + (kk),   (base) + bOff + 512); \
  } while(0)

#define G64_COMPUTE(base) do { \
    bfrag av[4], bv[2]; \
    _Pragma("unroll") \
    for (int i=0;i<4;++i) \
      av[i] = *(const bfrag*)&(base)[(16*i + lm)*32 + qs]; \
    _Pragma("unroll") \
    for (int j=0;j<2;++j) \
      bv[j] = *(const bfrag*)&(base)[2048 + (wv*32 + 16*j + lm)*32 + qs]; \
    _Pragma("unroll") \
    for (int i=0;i<4;++i){ \
      _Pragma("unroll") \
      for (int j=0;j<2;++j) \
        acc[i][j] = __builtin_amdgcn_mfma_f32_16x16x32_bf16(av[i], bv[j], acc[i][j], 0,0,0); \
    } \
  } while(0)

  u16* b0 = &SH[0][0];
  u16* b1 = &SH[1][0];
  u16* b2 = &SH[2][0];
  G64_STAGE(b0, 0);
  G64_STAGE(b1, 32);
  for (int k0 = 0; k0 + 64 < 1024; k0 += 32){
    G64_STAGE(b2, k0 + 64);
    asm volatile("s_waitcnt vmcnt(6)" ::: "memory");
    __builtin_amdgcn_s_barrier();
    __builtin_amdgcn_sched_barrier(0);
    G64_COMPUTE(b0);
    __builtin_amdgcn_sched_barrier(0);
    __builtin_amdgcn_s_barrier();
    u16* t = b0; b0 = b1; b1 = b2; b2 = t;
  }
  asm volatile("s_waitcnt vmcnt(3)" ::: "memory");
  __builtin_amdgcn_s_barrier();
  __builtin_amdgcn_sched_barrier(0);
  G64_COMPUTE(b0);
  asm volatile("s_waitcnt vmcnt(0)" ::: "memory");
  __builtin_amdgcn_s_barrier();
  __builtin_amdgcn_sched_barrier(0);
  G64_COMPUTE(b1);
  __syncthreads();
#undef G64_STAGE
#undef G64_COMPUTE

  // stage raw g1 [128 cols][64 ch] (stride 72) into SH
  u16* Tg = &SH[0][0];                 // 128*72 = 9216 u16 = 18KB
  #pragma unroll
  for (int i=0;i<4;++i){
    float4 bb = *(const float4*)&bias[16*i + quad*4];
    float b4[4] = {bb.x,bb.y,bb.z,bb.w};
    #pragma unroll
    for (int j=0;j<2;++j){
      int col = wv*32 + 16*j + lm;
      #pragma unroll
      for (int s2=0;s2<2;++s2){
        float v0 = acc[i][j][2*s2]   + b4[2*s2];
        float v1 = acc[i][j][2*s2+1] + b4[2*s2+1];
        unsigned int dw = (unsigned int)f2bf(v0) | ((unsigned int)f2bf(v1) << 16);
        *(unsigned int*)&Tg[col*72 + 16*i + quad*4 + 2*s2] = dw;
      }
    }
  }
  // stage head weights into LDS above Tg (byte off 18432; 1281 floats = 5KB)
  float* HW = (float*)(&SH[0][0] + 9216);
  if (tid < 64){ HW[tid] = gl1_g[tid]; HW[64+tid] = gl1_b[tid]; }
  for (int i = tid; i < 1024; i += 256) HW[128+i] = g2_w[i];
  if (tid < 16){ HW[1152+tid]=g2_b[tid]; HW[1168+tid]=gl2_g[tid]; HW[1184+tid]=gl2_b[tid]; }
  if (tid >= 64 && tid < 128) HW[1200 + tid-64] = g3_w[tid-64];
  if (tid >= 128 && tid < 132){
    int q = tid - 128;
    HW[1264+q]=g3_b[q]; HW[1268+q]=gl3_g[q]; HW[1272+q]=gl3_b[q];
    HW[1276+q] = g4_w[q] - g4_w[4+q];
  }
  if (tid == 132) HW[1280] = has_g4b ? (g4_b[0] - g4_b[1]) : 0.f;
  __syncthreads();

  if (tid < 128){
    const u16* gc = &Tg[tid*72];
    float a1[64]; float s=0.f;
    #pragma unroll
    for (int c0=0;c0<64;c0+=8){
      uint4 w = *(const uint4*)(gc + c0);
      const u16* wp = (const u16*)&w;
      #pragma unroll
      for (int m=0;m<8;++m){ a1[c0+m] = bf2f(wp[m]); s += a1[c0+m]; }
    }
    float m = s*(1.f/64.f); float s2=0.f;
    #pragma unroll
    for (int c=0;c<64;++c){ float d=a1[c]-m; s2+=d*d; }
    float rs = rsqrtf(s2*(1.f/64.f)+1e-5f);
    #pragma unroll
    for (int c=0;c<64;++c) a1[c] = gelu_f((a1[c]-m)*rs*HW[c]+HW[64+c]);

    float a2[16]; s=0.f;
    #pragma unroll
    for (int i=0;i<16;++i){
      float acc2 = HW[1152+i];
      #pragma unroll
      for (int o=0;o<64;++o) acc2 += HW[128 + i*64 + o]*a1[o];
      a2[i]=acc2; s+=acc2;
    }
    m = s*(1.f/16.f); s2=0.f;
    #pragma unroll
    for (int i=0;i<16;++i){ float d=a2[i]-m; s2+=d*d; }
    rs = rsqrtf(s2*(1.f/16.f)+1e-5f);
    float a2g[16];
    #pragma unroll
    for (int i=0;i<16;++i) a2g[i] = gelu_f((a2[i]-m)*rs*HW[1168+i]+HW[1184+i]);

    float a3[4]; s=0.f;
    #pragma unroll
    for (int i=0;i<4;++i){
      float acc3 = HW[1264+i];
      #pragma unroll
      for (int o=0;o<16;++o) acc3 += HW[1200 + i*16 + o]*a2g[o];
      a3[i]=acc3; s+=acc3;
    }
    m = s*0.25f; s2=0.f;
    #pragma unroll
    for (int i=0;i<4;++i){ float d=a3[i]-m; s2+=d*d; }
    rs = rsqrtf(s2*0.25f+1e-5f);
    float z = HW[1280];
    #pragma unroll
    for (int i=0;i<4;++i) z += HW[1276+i]*gelu_f((a3[i]-m)*rs*HW[1268+i]+HW[1272+i]);
    Outp[j0_global + bj*128 + tid] = 1.f/(1.f+expf(-z));
  }
}

// ---- LN over 512 ch, wave-per-column; bf16 in, bf16 out into XYbT y-half --
__global__ __launch_bounds__(256) void k_lnT(
    const u16* __restrict__ t2T,
    const float* __restrict__ gamma, const float* __restrict__ beta,
    u16* __restrict__ XYbT)
{
  __shared__ float gam[512], bet[512];
  const int tid = threadIdx.x;
  for (int c = tid; c < 512; c += 256){ gam[c]=gamma[c]; bet[c]=beta[c]; }
  __syncthreads();
  const int lane = tid & 63, wv = tid >> 6;
  const int j = blockIdx.x*4 + wv;
  uint4 w = *(const uint4*)(t2T + (size_t)j*512 + lane*8);
  const u16* wp = (const u16*)&w;
  float vv[8];
  #pragma unroll
  for (int m=0;m<8;++m) vv[m] = bf2f(wp[m]);
  float s = 0.f, s2 = 0.f;
  #pragma unroll
  for (int m=0;m<8;++m){ s += vv[m]; s2 += vv[m]*vv[m]; }
  #pragma unroll
  for (int off = 32; off; off >>= 1){
    s  += __shfl_xor(s,  off, 64);
    s2 += __shfl_xor(s2, off, 64);
  }
  float mean = s*(1.f/512.f);
  float rs = rsqrtf(s2*(1.f/512.f) - mean*mean + 1e-5f);
  u16 ob[8];
  #pragma unroll
  for (int m=0;m<8;++m){
    int c = lane*8 + m;
    ob[m] = f2bf((vv[m]-mean)*rs*gam[c] + bet[c]);
  }
  *(uint4*)&XYbT[(size_t)j*1024 + 512 + lane*8] = *(uint4*)ob;
}

extern "C" void kernel_launch(void* const* d_in, const int* in_sizes, int n_in,
                              void* d_out, int out_size, void* d_ws, size_t ws_size,
                              hipStream_t stream)
{
  const float* gtok  = (const float*)d_in[0];
  const float* x     = (const float*)d_in[1];
  const float* ws1_w = (const float*)d_in[2];
  const float* ws1_b = (const float*)d_in[3];
  const float* ws2_w = (const float*)d_in[4];
  const float* ws2_b = (const float*)d_in[5];
  const float* wc1_w = (const float*)d_in[6];
  const float* wc1_b = (const float*)d_in[7];
  const float* wc2_w = (const float*)d_in[8];
  const float* wc2_b = (const float*)d_in[9];
  const float* q_w   = (const float*)d_in[10];
  const float* q_b   = (const float*)d_in[11];
  const float* k_w   = (const float*)d_in[12];
  const float* v_w   = (const float*)d_in[14];
  const float* v_b   = (const float*)d_in[15];
  const float* merge_w = (const float*)d_in[16];
  const float* merge_b = (const float*)d_in[17];
  const float* m1_w  = (const float*)d_in[18];
  const float* m1_b  = (const float*)d_in[19];
  const float* m2_w  = (const float*)d_in[20];
  const float* m2_b  = (const float*)d_in[21];
  const float* n0_g  = (const float*)d_in[22];
  const float* n0_b  = (const float*)d_in[23];
  const float* n1_g  = (const float*)d_in[24];
  const float* n1_b  = (const float*)d_in[25];
  const float* g1_w  = (const float*)d_in[26];
  const float* g1_b  = (const float*)d_in[27];
  const float* gl1_g = (const float*)d_in[28];
  const float* gl1_b = (const float*)d_in[29];
  const float* g2_w  = (const float*)d_in[30];
  const float* g2_b  = (const float*)d_in[31];
  const float* gl2_g = (const float*)d_in[32];
  const float* gl2_b = (const float*)d_in[33];
  const float* g3_w  = (const float*)d_in[34];
  const float* g3_b  = (const float*)d_in[35];
  const float* gl3_g = (const float*)d_in[36];
  const float* gl3_b = (const float*)d_in[37];
  const float* g4_w  = (const float*)d_in[38];
  const float* g4_b  = (n_in > 39) ? (const float*)d_in[39] : nullptr;

  const int TOT = 65536;
  const size_t PRE_BYTES = (size_t)16 * PRE_STRIDE * 4;
  const size_t GT1_B = 65536, HID_B = 262144, GT2_B = 65536;
  const size_t DK_B = 32768, DV_B = 32768, V1L_B = 32768;
  const size_t WB1_B = (size_t)1024*1024*2;
  const size_t WB2_B = (size_t)512*1024*2;
  const size_t WG_B  = (size_t)64*1024*2;
  const size_t FIXED = PRE_BYTES + GT1_B + HID_B + GT2_B + DK_B + DV_B + V1L_B
                     + WB1_B + WB2_B + WG_B;
  // per-chunk: XYbT 2048C + T1bT 2048C + T2bT 1024C = 5120C bytes
  int C = 65536;
  while (C > 4096 && FIXED + (size_t)5120*C > ws_size) C >>= 1;
  const int nch = TOT / C;

  char* wsb = (char*)d_ws;
  size_t off = 0;
  float* PRE = (float*)(wsb + off); off += PRE_BYTES;
  float* GT1 = (float*)(wsb + off); off += GT1_B;
  float* HID = (float*)(wsb + off); off += HID_B;
  float* GT2 = (float*)(wsb + off); off += GT2_B;
  float* DK  = (float*)(wsb + off); off += DK_B;
  float* DV  = (float*)(wsb + off); off += DV_B;
  float* V1L = (float*)(wsb + off); off += V1L_B;
  u16* Wb1   = (u16*)(wsb + off);   off += WB1_B;
  u16* Wb2   = (u16*)(wsb + off);   off += WB2_B;
  u16* Wg    = (u16*)(wsb + off);   off += WG_B;
  u16* XYbT  = (u16*)(wsb + off);   off += (size_t)2048*C;  // [C][1024] bf16
  u16* T1bT  = (u16*)(wsb + off);   off += (size_t)2048*C;  // [C][1024] bf16
  u16* T2bT  = (u16*)(wsb + off);   off += (size_t)1024*C;  // [C][512] bf16

  dim3 blk(256);
  hipLaunchKernelGGL(kcvt, dim3(512), blk, 0, stream, m1_w, Wb1, 1024*1024/8);
  hipLaunchKernelGGL(kcvt, dim3(256), blk, 0, stream, m2_w, Wb2, 512*1024/8);
  hipLaunchKernelGGL(kcvt_dup, dim3(256), blk, 0, stream, g1_w, Wg);
  hipLaunchKernelGGL(k0a_mlps, dim3(16,2), blk, 0, stream,
      gtok, ws1_w, ws1_b, ws2_w, ws2_b, GT1);
  hipLaunchKernelGGL(k0b_fc1, dim3(16,8), blk, 0, stream, GT1, wc1_w, wc1_b, HID);
  hipLaunchKernelGGL(k0c_fc2, dim3(16,2), blk, 0, stream, GT1, HID, wc2_w, wc2_b, GT2);
  hipLaunchKernelGGL(k0d_kv,  dim3(16,2), blk, 0, stream, GT2, k_w, v_w, v_b, DK, DV, V1L);
  hipLaunchKernelGGL(k0e_qpre, dim3(16,2), blk, 0, stream, DK, q_w, q_b, PRE);
  hipLaunchKernelGGL(k0f_mpre, dim3(16,2), blk, 0, stream, DV, V1L, merge_w, merge_b, PRE);

  for (int ch = 0; ch < nch; ++ch){
    const int j0 = ch * C;
    // x->bf16 + attn + merge + LN(n0) in one pass over x -> XYbT
    hipLaunchKernelGGL(k1_fused, dim3(C/64), blk, 0, stream,
        x, PRE, n0_g, n0_b, j0, XYbT);
    // t1 = gelu(m1 @ XY + b) -> T1bT  (M=1024, nbi=8)
    hipLaunchKernelGGL(mfma_gemm_p, dim3(8*(C/128)), blk, 0, stream,
        Wb1, m1_b, XYbT, 1024, 1024, T1bT, 1, 3);
    // t2 = m2 @ t1 + b -> T2bT       (M=512, nbi=4)
    hipLaunchKernelGGL(mfma_gemm_p, dim3(4*(C/128)), blk, 0, stream,
        Wb2, m2_b, T1bT, 1024, 512, T2bT, 0, 2);
    // LN(t2; n1) -> bf16, overwrite y-half of XYbT (x-half stays = x bf16)
    hipLaunchKernelGGL(k_lnT, dim3(C/4), blk, 0, stream, T2bT, n1_g, n1_b, XYbT);
    // g1 GEMM + fused head -> d_out directly
    hipLaunchKernelGGL(mfma_g64h, dim3(C/128), blk, 0, stream,
        Wg, g1_b, XYbT,
        gl1_g, gl1_b, g2_w, g2_b, gl2_g, gl2_b,
        g3_w, g3_b, gl3_g, gl3_b,
        g4_w, g4_b ? g4_b : g4_w, g4_b ? 1 : 0, (float*)d_out, j0);
  }
}

// Round 13
// 894.457 us; speedup vs baseline: 1.0250x; 1.0206x over previous
//
#include <hip/hip_runtime.h>
#include <math.h>

typedef unsigned short u16;
typedef unsigned int u32;
typedef __attribute__((ext_vector_type(8))) short bfrag;   // 8 bf16 (4 VGPRs)
typedef __attribute__((ext_vector_type(4))) float f32x4;

// fast gelu: erf(z) via Abramowitz-Stegun 7.1.26 (|eps|<=1.5e-7), z = x/sqrt(2)
__device__ __forceinline__ float gelu_f(float x){
  float z = fabsf(x) * 0.70710678118654752440f;
  float t = __builtin_amdgcn_rcpf(1.0f + 0.3275911f*z);
  float p = t*(0.254829592f + t*(-0.284496736f + t*(1.421413741f
            + t*(-1.453152027f + t*1.061405429f))));
  float e = __expf(-z*z);
  float er = copysignf(1.0f - p*e, x);
  return 0.5f * x * (1.0f + er);
}
__device__ __forceinline__ u16 f2bf(float f){
  union { float f; unsigned int i; } c; c.f = f;
  unsigned int i = c.i;
  return (u16)((i + 0x7FFFu + ((i >> 16) & 1u)) >> 16);
}
__device__ __forceinline__ float bf2f(u16 u){
  union { unsigned int i; float f; } c; c.i = ((unsigned int)u) << 16; return c.f;
}

// async global->LDS DMA, 16B per lane. LDS dest = wave-uniform base + lane*16B.
__device__ __forceinline__ void gload_lds16(const u16* g, u16* l){
  __builtin_amdgcn_global_load_lds(
      (const __attribute__((address_space(1))) u32*)(g),
      (__attribute__((address_space(3))) u32*)(l),
      16, 0, 0);
}

struct F8 { float v[8]; };
__device__ __forceinline__ F8 load8f(const float* p){
  float4 a = *(const float4*)p; float4 b = *(const float4*)(p + 4);
  F8 r; r.v[0]=a.x; r.v[1]=a.y; r.v[2]=a.z; r.v[3]=a.w;
  r.v[4]=b.x; r.v[5]=b.y; r.v[6]=b.z; r.v[7]=b.w; return r;
}

#define PRE_STRIDE 4624

// ============ k0 phase A: mlp_s (2->256->2) + residual -> GT1 ==============
__global__ __launch_bounds__(256) void k0a_mlps(
    const float* __restrict__ gtok,
    const float* __restrict__ ws1_w, const float* __restrict__ ws1_b,
    const float* __restrict__ ws2_w, const float* __restrict__ ws2_b,
    float* __restrict__ GT1)
{
  __shared__ float sw1[256][2]; __shared__ float sb1[256];
  __shared__ float sw2[2][256];
  const int b = blockIdx.x;
  const int t = threadIdx.x;
  sw1[t][0] = ws1_w[2*t]; sw1[t][1] = ws1_w[2*t+1];
  sb1[t] = ws1_b[t];
  sw2[0][t] = ws2_w[t]; sw2[1][t] = ws2_w[256+t];
  __syncthreads();
  const int j = blockIdx.y*256 + t;
  const float a0 = gtok[b*1024 + 2*j], a1 = gtok[b*1024 + 2*j + 1];
  float s0 = ws2_b[0], s1 = ws2_b[1];
  #pragma unroll 4
  for (int o = 0; o < 256; ++o){
    float h = gelu_f(sw1[o][0]*a0 + sw1[o][1]*a1 + sb1[o]);
    s0 += sw2[0][o]*h; s1 += sw2[1][o]*h;
  }
  GT1[b*1024 + 2*j]     = a0 + s0;
  GT1[b*1024 + 2*j + 1] = a1 + s1;
}

// ============ k0 phase B: fc1 of mlp_c (512->2048) -> HID ==================
__global__ __launch_bounds__(256) void k0b_fc1(
    const float* __restrict__ GT1,
    const float* __restrict__ wc1_w, const float* __restrict__ wc1_b,
    float* __restrict__ HID)
{
  __shared__ float g[1024];
  const int b = blockIdx.x;
  const int t = threadIdx.x;
  for (int i = t; i < 1024; i += 256) g[i] = GT1[b*1024 + i];
  __syncthreads();
  const int o = blockIdx.y*256 + t;
  const float* wr = wc1_w + (size_t)o*512;
  float acc0 = wc1_b[o], acc1 = acc0;
  for (int d = 0; d < 512; d += 8){
    F8 w = load8f(wr + d);
    #pragma unroll
    for (int i = 0; i < 8; ++i){
      acc0 += w.v[i]*g[(d+i)*2];
      acc1 += w.v[i]*g[(d+i)*2+1];
    }
  }
  HID[b*4096 + o]        = gelu_f(acc0);
  HID[b*4096 + 2048 + o] = gelu_f(acc1);
}

// ============ k0 phase C: fc2 of mlp_c (2048->512) + residual -> GT2 =======
__global__ __launch_bounds__(256) void k0c_fc2(
    const float* __restrict__ GT1, const float* __restrict__ HID,
    const float* __restrict__ wc2_w, const float* __restrict__ wc2_b,
    float* __restrict__ GT2)
{
  __shared__ float h0[2048], h1[2048];
  const int b = blockIdx.x;
  const int t = threadIdx.x;
  for (int i = t; i < 2048; i += 256){
    h0[i] = HID[b*4096 + i]; h1[i] = HID[b*4096 + 2048 + i];
  }
  __syncthreads();
  const int d = blockIdx.y*256 + t;
  const float* wr = wc2_w + (size_t)d*2048;
  float acc0 = wc2_b[d], acc1 = acc0;
  for (int o = 0; o < 2048; o += 8){
    F8 w = load8f(wr + o);
    #pragma unroll
    for (int i = 0; i < 8; ++i){
      acc0 += w.v[i]*h0[o+i];
      acc1 += w.v[i]*h1[o+i];
    }
  }
  GT2[b*1024 + 2*d]     = GT1[b*1024 + 2*d]     + acc0;
  GT2[b*1024 + 2*d + 1] = GT1[b*1024 + 2*d + 1] + acc1;
}

// ============ k0 phase D: k,v -> dk, dv, v1l ================================
__global__ __launch_bounds__(256) void k0d_kv(
    const float* __restrict__ GT2,
    const float* __restrict__ k_w,
    const float* __restrict__ v_w, const float* __restrict__ v_b,
    float* __restrict__ DK, float* __restrict__ DV, float* __restrict__ V1L)
{
  __shared__ float g[1024];
  const int b = blockIdx.x;
  const int t = threadIdx.x;
  for (int i = t; i < 1024; i += 256) g[i] = GT2[b*1024 + i];
  __syncthreads();
  const int c = blockIdx.y*256 + t;
  const float* kr = k_w + (size_t)c*512;
  const float* vr = v_w + (size_t)c*512;
  float k0a=0.f,k1a=0.f,v0a=0.f,v1a=0.f;
  for (int d = 0; d < 512; d += 8){
    F8 kw = load8f(kr + d); F8 vw = load8f(vr + d);
    #pragma unroll
    for (int i = 0; i < 8; ++i){
      float g0 = g[(d+i)*2], g1 = g[(d+i)*2+1];
      k0a += kw.v[i]*g0; k1a += kw.v[i]*g1;
      v0a += vw.v[i]*g0; v1a += vw.v[i]*g1;
    }
  }
  DK[b*512 + c]  = k0a - k1a;
  DV[b*512 + c]  = v0a - v1a;
  V1L[b*512 + c] = v1a + v_b[c];
}

// ============ k0 phase E: wdiff + beta4 -> PRE ==============================
__global__ __launch_bounds__(256) void k0e_qpre(
    const float* __restrict__ DK,
    const float* __restrict__ q_w, const float* __restrict__ q_b,
    float* __restrict__ PRE)
{
  __shared__ float dkl[512];
  const int b = blockIdx.x;
  const int t = threadIdx.x;
  for (int i = t; i < 512; i += 256) dkl[i] = DK[b*512 + i];
  __syncthreads();
  const int i = blockIdx.y*256 + t;
  float w0=0.f,w1=0.f,w2=0.f,w3=0.f;
  for (int c = 0; c < 512; c += 4){
    w0 += dkl[c]  *q_w[(size_t)(c)  *512 + i];
    w1 += dkl[c+1]*q_w[(size_t)(c+1)*512 + i];
    w2 += dkl[c+2]*q_w[(size_t)(c+2)*512 + i];
    w3 += dkl[c+3]*q_w[(size_t)(c+3)*512 + i];
  }
  float* P = PRE + (size_t)b * PRE_STRIDE;
  P[0*512+i]=w0; P[1*512+i]=w1; P[2*512+i]=w2; P[3*512+i]=w3;
  if (blockIdx.y == 0 && t < 4){
    float bsum = 0.f;
    for (int c = t; c < 512; c += 4) bsum += dkl[c]*q_b[c];
    P[2048 + t] = bsum;
  }
}

// ============ k0 phase F: base + M -> PRE ===================================
__global__ __launch_bounds__(256) void k0f_mpre(
    const float* __restrict__ DV, const float* __restrict__ V1L,
    const float* __restrict__ merge_w, const float* __restrict__ merge_b,
    float* __restrict__ PRE)
{
  __shared__ float dvl[512], v1ll[512];
  const int b = blockIdx.x;
  const int t = threadIdx.x;
  for (int i = t; i < 512; i += 256){
    dvl[i] = DV[b*512 + i]; v1ll[i] = V1L[b*512 + i];
  }
  __syncthreads();
  const int r = blockIdx.y*256 + t;
  const float* mw = merge_w + (size_t)r*512;
  float ab = merge_b[r];
  float mh[4] = {0.f,0.f,0.f,0.f};
  for (int c = 0; c < 512; c += 8){
    F8 w = load8f(mw + c);
    #pragma unroll
    for (int i = 0; i < 8; ++i){
      ab += w.v[i]*v1ll[c+i];
      mh[i&3] += w.v[i]*dvl[c+i];
    }
  }
  float* P = PRE + (size_t)b * PRE_STRIDE;
  P[2064 + r] = ab;
  *(float4*)&P[2576 + r*4] = make_float4(mh[0],mh[1],mh[2],mh[3]);
}

// ---------------- convert fp32 -> bf16 (flat) ------------------------------
__global__ __launch_bounds__(256) void kcvt(const float* __restrict__ s,
                                            u16* __restrict__ d, int n8)
{
  int g = blockIdx.x*256 + threadIdx.x;
  if (g >= n8) return;
  F8 v = load8f(s + (size_t)g*8);
  u16 o[8];
  #pragma unroll
  for (int i=0;i<8;++i) o[i] = f2bf(v.v[i]);
  *(uint4*)(d + (size_t)g*8) = *(uint4*)o;
}

// ------- build Wg64 [64][1024] = [g1_w | g1_w] bf16 ------------------------
__global__ __launch_bounds__(256) void kcvt_dup(const float* __restrict__ g1w,
                                                u16* __restrict__ out)
{
  int idx = blockIdx.x*256 + threadIdx.x;      // 65536 total
  int r = idx >> 10, k = idx & 1023;
  out[idx] = f2bf(g1w[r*512 + (k & 511)]);
}

// ---- K1: one pass over x: XYbT[j][0..511]=x bf16, [512..1023]=attn+LN(n0) --
// 64 cols/block, 4-way channel split. Stores in 64B full-line bursts.
__global__ __launch_bounds__(256) void k1_fused(
    const float* __restrict__ x, const float* __restrict__ PRE,
    const float* __restrict__ n0_g, const float* __restrict__ n0_b,
    int j0_global, u16* __restrict__ XYbT)
{
  __shared__ float wd[4][512];
  __shared__ float bs[512];
  __shared__ float Mm[512][4];
  __shared__ float gam[512], bet[512];
  __shared__ float beta4[4];
  __shared__ float part[4][4][64];
  __shared__ float pstat[2][4][64];
  const int tid = threadIdx.x;
  const int cid = tid & 63;
  const int qtr = tid >> 6;
  const int jl = blockIdx.x*64 + cid;
  const int jg = j0_global + jl;
  const int b = jg >> 12, n = jg & 4095;   // 4096 % 64 == 0: no b-straddle
  const float* P = PRE + (size_t)b * PRE_STRIDE;
  for (int i = tid; i < 2048; i += 256) wd[i>>9][i&511] = P[i];
  if (tid < 4) beta4[tid] = P[2048 + tid];
  for (int i = tid; i < 512; i += 256){
    bs[i] = P[2064 + i]; gam[i] = n0_g[i]; bet[i] = n0_b[i];
  }
  for (int i = tid; i < 2048; i += 256) Mm[i>>2][i&3] = P[2576 + i];
  __syncthreads();
  const float* xc = x + (size_t)b*2097152 + n;
  u16* col = XYbT + (size_t)jl*1024;
  const int ibase = qtr*128;
  float l0=0.f, l1=0.f, l2=0.f, l3=0.f;
  for (int i0 = 0; i0 < 128; i0 += 32){
    u16 ob[32];
    #pragma unroll
    for (int m = 0; m < 32; ++m){
      int i = ibase + i0 + m;
      float xv = xc[(size_t)i*4096];
      ob[m] = f2bf(xv);
      l0 += wd[0][i]*xv; l1 += wd[1][i]*xv;
      l2 += wd[2][i]*xv; l3 += wd[3][i]*xv;
    }
    #pragma unroll
    for (int q = 0; q < 4; ++q)            // one full 64B line, back-to-back
      *(uint4*)&col[ibase + i0 + 8*q] = *(uint4*)&ob[8*q];
  }
  part[0][qtr][cid] = l0; part[1][qtr][cid] = l1;
  part[2][qtr][cid] = l2; part[3][qtr][cid] = l3;
  __syncthreads();
  l0 = part[0][0][cid] + part[0][1][cid] + part[0][2][cid] + part[0][3][cid] + beta4[0];
  l1 = part[1][0][cid] + part[1][1][cid] + part[1][2][cid] + part[1][3][cid] + beta4[1];
  l2 = part[2][0][cid] + part[2][1][cid] + part[2][2][cid] + part[2][3][cid] + beta4[2];
  l3 = part[3][0][cid] + part[3][1][cid] + part[3][2][cid] + part[3][3][cid] + beta4[3];
  const float sc = 0.0883883476483184405f;
  float p0 = 1.f/(1.f+expf(-sc*l0));
  float p1 = 1.f/(1.f+expf(-sc*l1));
  float p2 = 1.f/(1.f+expf(-sc*l2));
  float p3 = 1.f/(1.f+expf(-sc*l3));
  float s=0.f, s2=0.f;
  for (int c = ibase; c < ibase + 128; ++c){
    float m = bs[c] + Mm[c][0]*p0 + Mm[c][1]*p1 + Mm[c][2]*p2 + Mm[c][3]*p3;
    s += m; s2 += m*m;
  }
  pstat[0][qtr][cid] = s; pstat[1][qtr][cid] = s2;
  __syncthreads();
  s  = pstat[0][0][cid] + pstat[0][1][cid] + pstat[0][2][cid] + pstat[0][3][cid];
  s2 = pstat[1][0][cid] + pstat[1][1][cid] + pstat[1][2][cid] + pstat[1][3][cid];
  float mean = s*(1.f/512.f);
  float rs = rsqrtf(s2*(1.f/512.f) - mean*mean + 1e-5f);
  for (int c0 = 0; c0 < 128; c0 += 32){
    u16 ob[32];
    #pragma unroll
    for (int m = 0; m < 32; ++m){
      int c = ibase + c0 + m;
      float v = bs[c] + Mm[c][0]*p0 + Mm[c][1]*p1 + Mm[c][2]*p2 + Mm[c][3]*p3;
      ob[m] = f2bf((v - mean)*rs*gam[c] + bet[c]);
    }
    #pragma unroll
    for (int q = 0; q < 4; ++q)            // full 64B line, back-to-back
      *(uint4*)&col[512 + ibase + c0 + 8*q] = *(uint4*)&ob[8*q];
  }
}

// --------- MFMA GEMM: gload_lds DMA, depth-2 pipeline, T2 LDS swizzle ------
// Round-10 verified best (m1=198us, end-to-end 889us): 3 buffers, two-barrier
// K-loop, setprio around MFMA (A/B-verified +8% in this structure: 3 blocks/CU
// gives cross-block phase skew for the scheduler to arbitrate), single-pass
// 128x136 epilogue.
__global__ __launch_bounds__(256) void mfma_gemm_p(
    const u16* __restrict__ Wb, const float* __restrict__ bias,
    const u16* __restrict__ XT, int K, int M,
    u16* __restrict__ Out, int do_gelu, int log2nbi)
{
  __shared__ __align__(16) u16 SH[3][8192];  // per buf: A[128][32] | B[128][32]
  const int tid = threadIdx.x;
  const int lane = tid & 63;
  const int wv = __builtin_amdgcn_readfirstlane(tid >> 6);
  const int id = blockIdx.x;
  const int bi = (id >> 3) & ((1 << log2nbi) - 1);
  const int bj = (id & 7) + 8 * (id >> (3 + log2nbi));
  const int roff = (wv >> 1) * 64;
  const int noff = (wv & 1) * 64;
  const int lm = lane & 15, quad = lane >> 4;
  const int qs = (quad ^ ((lm >> 1) & 3)) * 8;   // swizzled 16B slot (read)

  f32x4 acc[4][4];
  #pragma unroll
  for (int i=0;i<4;++i){
    #pragma unroll
    for (int j=0;j<4;++j) acc[i][j] = (f32x4){0.f,0.f,0.f,0.f};
  }

  // DMA map: lane -> row r16=lane>>2 (16 rows/instr), 16B slot lane&3.
  // Global k-slot pre-swizzled so linear LDS write lands swizzled layout.
  const int r16 = lane >> 2;
  const int kc  = (((lane & 3) ^ ((lane >> 3) & 3))) * 8;
  const u16* aG = Wb + (size_t)(bi*128 + wv*32 + r16)*K + kc;
  const u16* bG = XT + (size_t)(bj*128 + wv*32 + r16)*1024 + kc;
  const int aOff = wv*1024;          // (wv*32)*32 u16
  const int bOff = 4096 + wv*1024;

#define GP_STAGE(base, kk) do { \
    gload_lds16(aG + (kk),                 (base) + aOff); \
    gload_lds16(aG + (size_t)16*K + (kk),  (base) + aOff + 512); \
    gload_lds16(bG + (kk),                 (base) + bOff); \
    gload_lds16(bG + 16*1024 + (kk),       (base) + bOff + 512); \
  } while(0)

#define GP_COMPUTE(base) do { \
    bfrag av[4], bv[4]; \
    _Pragma("unroll") \
    for (int i=0;i<4;++i) \
      av[i] = *(const bfrag*)&(base)[(roff + 16*i + lm)*32 + qs]; \
    _Pragma("unroll") \
    for (int j=0;j<4;++j) \
      bv[j] = *(const bfrag*)&(base)[4096 + (noff + 16*j + lm)*32 + qs]; \
    __builtin_amdgcn_s_setprio(1); \
    _Pragma("unroll") \
    for (int i=0;i<4;++i){ \
      _Pragma("unroll") \
      for (int j=0;j<4;++j) \
        acc[i][j] = __builtin_amdgcn_mfma_f32_16x16x32_bf16(av[i], bv[j], acc[i][j], 0,0,0); \
    } \
    __builtin_amdgcn_s_setprio(0); \
  } while(0)

  u16* b0 = &SH[0][0];
  u16* b1 = &SH[1][0];
  u16* b2 = &SH[2][0];
  GP_STAGE(b0, 0);
  GP_STAGE(b1, 32);
  for (int k0 = 0; k0 + 64 < K; k0 += 32){
    GP_STAGE(b2, k0 + 64);                       // prefetch 2 tiles ahead
    asm volatile("s_waitcnt vmcnt(8)" ::: "memory");  // tile k0 resident
    __builtin_amdgcn_s_barrier();
    __builtin_amdgcn_sched_barrier(0);
    GP_COMPUTE(b0);
    __builtin_amdgcn_sched_barrier(0);
    __builtin_amdgcn_s_barrier();                // reads done before overwrite
    u16* t = b0; b0 = b1; b1 = b2; b2 = t;
  }
  asm volatile("s_waitcnt vmcnt(4)" ::: "memory");
  __builtin_amdgcn_s_barrier();
  __builtin_amdgcn_sched_barrier(0);
  GP_COMPUTE(b0);
  asm volatile("s_waitcnt vmcnt(0)" ::: "memory");
  __builtin_amdgcn_s_barrier();
  __builtin_amdgcn_sched_barrier(0);
  GP_COMPUTE(b1);
  __syncthreads();
#undef GP_STAGE
#undef GP_COMPUTE

  // single-pass epilogue: all waves write their frags into 128x136 transpose
  u16* Tt = &SH[0][0];                 // 128*136 = 17408 u16 <= 24576
  #pragma unroll
  for (int i=0;i<4;++i){
    float4 bb = *(const float4*)&bias[bi*128 + roff + 16*i + quad*4];
    float b4[4] = {bb.x,bb.y,bb.z,bb.w};
    #pragma unroll
    for (int j=0;j<4;++j){
      int colr = noff + 16*j + lm;
      #pragma unroll
      for (int s2=0;s2<2;++s2){
        float v0 = acc[i][j][2*s2]   + b4[2*s2];
        float v1 = acc[i][j][2*s2+1] + b4[2*s2+1];
        if (do_gelu){ v0 = gelu_f(v0); v1 = gelu_f(v1); }
        unsigned int dw = (unsigned int)f2bf(v0) | ((unsigned int)f2bf(v1) << 16);
        *(unsigned int*)&Tt[colr*136 + roff + 16*i + quad*4 + 2*s2] = dw;
      }
    }
  }
  __syncthreads();
  {
    int c = tid >> 1, q = tid & 1;     // col 0..127, 64-u16 half
    u16* dst = Out + (size_t)(bj*128 + c)*M + bi*128 + q*64;
    const u16* src = &Tt[c*136 + q*64];
    #pragma unroll
    for (int m=0;m<8;++m)
      *(uint4*)(dst + m*8) = *(const uint4*)(src + m*8);
  }
}

// ---- MFMA g1 GEMM + FUSED HEAD (T2 swizzle, round-10 loop, setprio) -------
__global__ __launch_bounds__(256) void mfma_g64h(
    const u16* __restrict__ Wg, const float* __restrict__ bias,
    const u16* __restrict__ XT,
    const float* __restrict__ gl1_g, const float* __restrict__ gl1_b,
    const float* __restrict__ g2_w, const float* __restrict__ g2_b,
    const float* __restrict__ gl2_g, const float* __restrict__ gl2_b,
    const float* __restrict__ g3_w, const float* __restrict__ g3_b,
    const float* __restrict__ gl3_g, const float* __restrict__ gl3_b,
    const float* __restrict__ g4_w, const float* __restrict__ g4_b, int has_g4b,
    float* __restrict__ Outp, int j0_global)
{
  __shared__ __align__(16) u16 SH[3][6144];  // per buf: A[64][32] | B[128][32]
  const int tid = threadIdx.x;
  const int lane = tid & 63;
  const int wv = __builtin_amdgcn_readfirstlane(tid >> 6);
  const int bj = blockIdx.x;
  const int lm = lane & 15, quad = lane >> 4;
  const int qs = (quad ^ ((lm >> 1) & 3)) * 8;   // swizzled 16B slot (read)

  f32x4 acc[4][2];
  #pragma unroll
  for (int i=0;i<4;++i){
    #pragma unroll
    for (int j=0;j<2;++j) acc[i][j] = (f32x4){0.f,0.f,0.f,0.f};
  }
  const int r16 = lane >> 2;
  const int kc  = (((lane & 3) ^ ((lane >> 3) & 3))) * 8;
  const u16* aG = Wg + (size_t)(wv*16 + r16)*1024 + kc;
  const u16* bG = XT + (size_t)(bj*128 + wv*32 + r16)*1024 + kc;
  const int aOff = wv*512;            // (wv*16)*32
  const int bOff = 2048 + wv*1024;    // B area + (wv*32)*32

#define G64_STAGE(base, kk) do { \
    gload_lds16(aG + (kk),             (base) + aOff); \
    gload_lds16(bG + (kk),             (base) + bOff); \
    gload_lds16(bG + 16*1024 + (kk),   (base) + bOff + 512); \
  } while(0)

#define G64_COMPUTE(base) do { \
    bfrag av[4], bv[2]; \
    _Pragma("unroll") \
    for (int i=0;i<4;++i) \
      av[i] = *(const bfrag*)&(base)[(16*i + lm)*32 + qs]; \
    _Pragma("unroll") \
    for (int j=0;j<2;++j) \
      bv[j] = *(const bfrag*)&(base)[2048 + (wv*32 + 16*j + lm)*32 + qs]; \
    __builtin_amdgcn_s_setprio(1); \
    _Pragma("unroll") \
    for (int i=0;i<4;++i){ \
      _Pragma("unroll") \
      for (int j=0;j<2;++j) \
        acc[i][j] = __builtin_amdgcn_mfma_f32_16x16x32_bf16(av[i], bv[j], acc[i][j], 0,0,0); \
    } \
    __builtin_amdgcn_s_setprio(0); \
  } while(0)

  u16* b0 = &SH[0][0];
  u16* b1 = &SH[1][0];
  u16* b2 = &SH[2][0];
  G64_STAGE(b0, 0);
  G64_STAGE(b1, 32);
  for (int k0 = 0; k0 + 64 < 1024; k0 += 32){
    G64_STAGE(b2, k0 + 64);
    asm volatile("s_waitcnt vmcnt(6)" ::: "memory");
    __builtin_amdgcn_s_barrier();
    __builtin_amdgcn_sched_barrier(0);
    G64_COMPUTE(b0);
    __builtin_amdgcn_sched_barrier(0);
    __builtin_amdgcn_s_barrier();
    u16* t = b0; b0 = b1; b1 = b2; b2 = t;
  }
  asm volatile("s_waitcnt vmcnt(3)" ::: "memory");
  __builtin_amdgcn_s_barrier();
  __builtin_amdgcn_sched_barrier(0);
  G64_COMPUTE(b0);
  asm volatile("s_waitcnt vmcnt(0)" ::: "memory");
  __builtin_amdgcn_s_barrier();
  __builtin_amdgcn_sched_barrier(0);
  G64_COMPUTE(b1);
  __syncthreads();
#undef G64_STAGE
#undef G64_COMPUTE

  // stage raw g1 [128 cols][64 ch] (stride 72) into SH
  u16* Tg = &SH[0][0];                 // 128*72 = 9216 u16 = 18KB
  #pragma unroll
  for (int i=0;i<4;++i){
    float4 bb = *(const float4*)&bias[16*i + quad*4];
    float b4[4] = {bb.x,bb.y,bb.z,bb.w};
    #pragma unroll
    for (int j=0;j<2;++j){
      int col = wv*32 + 16*j + lm;
      #pragma unroll
      for (int s2=0;s2<2;++s2){
        float v0 = acc[i][j][2*s2]   + b4[2*s2];
        float v1 = acc[i][j][2*s2+1] + b4[2*s2+1];
        unsigned int dw = (unsigned int)f2bf(v0) | ((unsigned int)f2bf(v1) << 16);
        *(unsigned int*)&Tg[col*72 + 16*i + quad*4 + 2*s2] = dw;
      }
    }
  }
  // stage head weights into LDS above Tg (byte off 18432; 1281 floats = 5KB)
  float* HW = (float*)(&SH[0][0] + 9216);
  if (tid < 64){ HW[tid] = gl1_g[tid]; HW[64+tid] = gl1_b[tid]; }
  for (int i = tid; i < 1024; i += 256) HW[128+i] = g2_w[i];
  if (tid < 16){ HW[1152+tid]=g2_b[tid]; HW[1168+tid]=gl2_g[tid]; HW[1184+tid]=gl2_b[tid]; }
  if (tid >= 64 && tid < 128) HW[1200 + tid-64] = g3_w[tid-64];
  if (tid >= 128 && tid < 132){
    int q = tid - 128;
    HW[1264+q]=g3_b[q]; HW[1268+q]=gl3_g[q]; HW[1272+q]=gl3_b[q];
    HW[1276+q] = g4_w[q] - g4_w[4+q];
  }
  if (tid == 132) HW[1280] = has_g4b ? (g4_b[0] - g4_b[1]) : 0.f;
  __syncthreads();

  if (tid < 128){
    const u16* gc = &Tg[tid*72];
    float a1[64]; float s=0.f;
    #pragma unroll
    for (int c0=0;c0<64;c0+=8){
      uint4 w = *(const uint4*)(gc + c0);
      const u16* wp = (const u16*)&w;
      #pragma unroll
      for (int m=0;m<8;++m){ a1[c0+m] = bf2f(wp[m]); s += a1[c0+m]; }
    }
    float m = s*(1.f/64.f); float s2=0.f;
    #pragma unroll
    for (int c=0;c<64;++c){ float d=a1[c]-m; s2+=d*d; }
    float rs = rsqrtf(s2*(1.f/64.f)+1e-5f);
    #pragma unroll
    for (int c=0;c<64;++c) a1[c] = gelu_f((a1[c]-m)*rs*HW[c]+HW[64+c]);

    float a2[16]; s=0.f;
    #pragma unroll
    for (int i=0;i<16;++i){
      float acc2 = HW[1152+i];
      #pragma unroll
      for (int o=0;o<64;++o) acc2 += HW[128 + i*64 + o]*a1[o];
      a2[i]=acc2; s+=acc2;
    }
    m = s*(1.f/16.f); s2=0.f;
    #pragma unroll
    for (int i=0;i<16;++i){ float d=a2[i]-m; s2+=d*d; }
    rs = rsqrtf(s2*(1.f/16.f)+1e-5f);
    float a2g[16];
    #pragma unroll
    for (int i=0;i<16;++i) a2g[i] = gelu_f((a2[i]-m)*rs*HW[1168+i]+HW[1184+i]);

    float a3[4]; s=0.f;
    #pragma unroll
    for (int i=0;i<4;++i){
      float acc3 = HW[1264+i];
      #pragma unroll
      for (int o=0;o<16;++o) acc3 += HW[1200 + i*16 + o]*a2g[o];
      a3[i]=acc3; s+=acc3;
    }
    m = s*0.25f; s2=0.f;
    #pragma unroll
    for (int i=0;i<4;++i){ float d=a3[i]-m; s2+=d*d; }
    rs = rsqrtf(s2*0.25f+1e-5f);
    float z = HW[1280];
    #pragma unroll
    for (int i=0;i<4;++i) z += HW[1276+i]*gelu_f((a3[i]-m)*rs*HW[1268+i]+HW[1272+i]);
    Outp[j0_global + bj*128 + tid] = 1.f/(1.f+expf(-z));
  }
}

// ---- LN over 512 ch, wave-per-column; bf16 in, bf16 out into XYbT y-half --
__global__ __launch_bounds__(256) void k_lnT(
    const u16* __restrict__ t2T,
    const float* __restrict__ gamma, const float* __restrict__ beta,
    u16* __restrict__ XYbT)
{
  __shared__ float gam[512], bet[512];
  const int tid = threadIdx.x;
  for (int c = tid; c < 512; c += 256){ gam[c]=gamma[c]; bet[c]=beta[c]; }
  __syncthreads();
  const int lane = tid & 63, wv = tid >> 6;
  const int j = blockIdx.x*4 + wv;
  uint4 w = *(const uint4*)(t2T + (size_t)j*512 + lane*8);
  const u16* wp = (const u16*)&w;
  float vv[8];
  #pragma unroll
  for (int m=0;m<8;++m) vv[m] = bf2f(wp[m]);
  float s = 0.f, s2 = 0.f;
  #pragma unroll
  for (int m=0;m<8;++m){ s += vv[m]; s2 += vv[m]*vv[m]; }
  #pragma unroll
  for (int off = 32; off; off >>= 1){
    s  += __shfl_xor(s,  off, 64);
    s2 += __shfl_xor(s2, off, 64);
  }
  float mean = s*(1.f/512.f);
  float rs = rsqrtf(s2*(1.f/512.f) - mean*mean + 1e-5f);
  u16 ob[8];
  #pragma unroll
  for (int m=0;m<8;++m){
    int c = lane*8 + m;
    ob[m] = f2bf((vv[m]-mean)*rs*gam[c] + bet[c]);
  }
  *(uint4*)&XYbT[(size_t)j*1024 + 512 + lane*8] = *(uint4*)ob;
}

extern "C" void kernel_launch(void* const* d_in, const int* in_sizes, int n_in,
                              void* d_out, int out_size, void* d_ws, size_t ws_size,
                              hipStream_t stream)
{
  const float* gtok  = (const float*)d_in[0];
  const float* x     = (const float*)d_in[1];
  const float* ws1_w = (const float*)d_in[2];
  const float* ws1_b = (const float*)d_in[3];
  const float* ws2_w = (const float*)d_in[4];
  const float* ws2_b = (const float*)d_in[5];
  const float* wc1_w = (const float*)d_in[6];
  const float* wc1_b = (const float*)d_in[7];
  const float* wc2_w = (const float*)d_in[8];
  const float* wc2_b = (const float*)d_in[9];
  const float* q_w   = (const float*)d_in[10];
  const float* q_b   = (const float*)d_in[11];
  const float* k_w   = (const float*)d_in[12];
  const float* v_w   = (const float*)d_in[14];
  const float* v_b   = (const float*)d_in[15];
  const float* merge_w = (const float*)d_in[16];
  const float* merge_b = (const float*)d_in[17];
  const float* m1_w  = (const float*)d_in[18];
  const float* m1_b  = (const float*)d_in[19];
  const float* m2_w  = (const float*)d_in[20];
  const float* m2_b  = (const float*)d_in[21];
  const float* n0_g  = (const float*)d_in[22];
  const float* n0_b  = (const float*)d_in[23];
  const float* n1_g  = (const float*)d_in[24];
  const float* n1_b  = (const float*)d_in[25];
  const float* g1_w  = (const float*)d_in[26];
  const float* g1_b  = (const float*)d_in[27];
  const float* gl1_g = (const float*)d_in[28];
  const float* gl1_b = (const float*)d_in[29];
  const float* g2_w  = (const float*)d_in[30];
  const float* g2_b  = (const float*)d_in[31];
  const float* gl2_g = (const float*)d_in[32];
  const float* gl2_b = (const float*)d_in[33];
  const float* g3_w  = (const float*)d_in[34];
  const float* g3_b  = (const float*)d_in[35];
  const float* gl3_g = (const float*)d_in[36];
  const float* gl3_b = (const float*)d_in[37];
  const float* g4_w  = (const float*)d_in[38];
  const float* g4_b  = (n_in > 39) ? (const float*)d_in[39] : nullptr;

  const int TOT = 65536;
  const size_t PRE_BYTES = (size_t)16 * PRE_STRIDE * 4;
  const size_t GT1_B = 65536, HID_B = 262144, GT2_B = 65536;
  const size_t DK_B = 32768, DV_B = 32768, V1L_B = 32768;
  const size_t WB1_B = (size_t)1024*1024*2;
  const size_t WB2_B = (size_t)512*1024*2;
  const size_t WG_B  = (size_t)64*1024*2;
  const size_t FIXED = PRE_BYTES + GT1_B + HID_B + GT2_B + DK_B + DV_B + V1L_B
                     + WB1_B + WB2_B + WG_B;
  // per-chunk: XYbT 2048C + T1bT 2048C + T2bT 1024C = 5120C bytes
  int C = 65536;
  while (C > 4096 && FIXED + (size_t)5120*C > ws_size) C >>= 1;
  const int nch = TOT / C;

  char* wsb = (char*)d_ws;
  size_t off = 0;
  float* PRE = (float*)(wsb + off); off += PRE_BYTES;
  float* GT1 = (float*)(wsb + off); off += GT1_B;
  float* HID = (float*)(wsb + off); off += HID_B;
  float* GT2 = (float*)(wsb + off); off += GT2_B;
  float* DK  = (float*)(wsb + off); off += DK_B;
  float* DV  = (float*)(wsb + off); off += DV_B;
  float* V1L = (float*)(wsb + off); off += V1L_B;
  u16* Wb1   = (u16*)(wsb + off);   off += WB1_B;
  u16* Wb2   = (u16*)(wsb + off);   off += WB2_B;
  u16* Wg    = (u16*)(wsb + off);   off += WG_B;
  u16* XYbT  = (u16*)(wsb + off);   off += (size_t)2048*C;  // [C][1024] bf16
  u16* T1bT  = (u16*)(wsb + off);   off += (size_t)2048*C;  // [C][1024] bf16
  u16* T2bT  = (u16*)(wsb + off);   off += (size_t)1024*C;  // [C][512] bf16

  dim3 blk(256);
  hipLaunchKernelGGL(kcvt, dim3(512), blk, 0, stream, m1_w, Wb1, 1024*1024/8);
  hipLaunchKernelGGL(kcvt, dim3(256), blk, 0, stream, m2_w, Wb2, 512*1024/8);
  hipLaunchKernelGGL(kcvt_dup, dim3(256), blk, 0, stream, g1_w, Wg);
  hipLaunchKernelGGL(k0a_mlps, dim3(16,2), blk, 0, stream,
      gtok, ws1_w, ws1_b, ws2_w, ws2_b, GT1);
  hipLaunchKernelGGL(k0b_fc1, dim3(16,8), blk, 0, stream, GT1, wc1_w, wc1_b, HID);
  hipLaunchKernelGGL(k0c_fc2, dim3(16,2), blk, 0, stream, GT1, HID, wc2_w, wc2_b, GT2);
  hipLaunchKernelGGL(k0d_kv,  dim3(16,2), blk, 0, stream, GT2, k_w, v_w, v_b, DK, DV, V1L);
  hipLaunchKernelGGL(k0e_qpre, dim3(16,2), blk, 0, stream, DK, q_w, q_b, PRE);
  hipLaunchKernelGGL(k0f_mpre, dim3(16,2), blk, 0, stream, DV, V1L, merge_w, merge_b, PRE);

  for (int ch = 0; ch < nch; ++ch){
    const int j0 = ch * C;
    // x->bf16 + attn + merge + LN(n0) in one pass over x -> XYbT
    hipLaunchKernelGGL(k1_fused, dim3(C/64), blk, 0, stream,
        x, PRE, n0_g, n0_b, j0, XYbT);
    // t1 = gelu(m1 @ XY + b) -> T1bT  (M=1024, nbi=8)
    hipLaunchKernelGGL(mfma_gemm_p, dim3(8*(C/128)), blk, 0, stream,
        Wb1, m1_b, XYbT, 1024, 1024, T1bT, 1, 3);
    // t2 = m2 @ t1 + b -> T2bT       (M=512, nbi=4)
    hipLaunchKernelGGL(mfma_gemm_p, dim3(4*(C/128)), blk, 0, stream,
        Wb2, m2_b, T1bT, 1024, 512, T2bT, 0, 2);
    // LN(t2; n1) -> bf16, overwrite y-half of XYbT (x-half stays = x bf16)
    hipLaunchKernelGGL(k_lnT, dim3(C/4), blk, 0, stream, T2bT, n1_g, n1_b, XYbT);
    // g1 GEMM + fused head -> d_out directly
    hipLaunchKernelGGL(mfma_g64h, dim3(C/128), blk, 0, stream,
        Wg, g1_b, XYbT,
        gl1_g, gl1_b, g2_w, g2_b, gl2_g, gl2_b,
        g3_w, g3_b, gl3_g, gl3_b,
        g4_w, g4_b ? g4_b : g4_w, g4_b ? 1 : 0, (float*)d_out, j0);
  }
}

// Round 14
// 888.313 us; speedup vs baseline: 1.0321x; 1.0069x over previous
//
#include <hip/hip_runtime.h>
#include <math.h>

typedef unsigned short u16;
typedef unsigned int u32;
typedef __attribute__((ext_vector_type(8))) short bfrag;   // 8 bf16 (4 VGPRs)
typedef __attribute__((ext_vector_type(4))) float f32x4;

// fast gelu: erf(z) via Abramowitz-Stegun 7.1.26 (|eps|<=1.5e-7), z = x/sqrt(2)
__device__ __forceinline__ float gelu_f(float x){
  float z = fabsf(x) * 0.70710678118654752440f;
  float t = __builtin_amdgcn_rcpf(1.0f + 0.3275911f*z);
  float p = t*(0.254829592f + t*(-0.284496736f + t*(1.421413741f
            + t*(-1.453152027f + t*1.061405429f))));
  float e = __expf(-z*z);
  float er = copysignf(1.0f - p*e, x);
  return 0.5f * x * (1.0f + er);
}
__device__ __forceinline__ u16 f2bf(float f){
  union { float f; unsigned int i; } c; c.f = f;
  unsigned int i = c.i;
  return (u16)((i + 0x7FFFu + ((i >> 16) & 1u)) >> 16);
}
__device__ __forceinline__ float bf2f(u16 u){
  union { unsigned int i; float f; } c; c.i = ((unsigned int)u) << 16; return c.f;
}

// async global->LDS DMA, 16B per lane. LDS dest = wave-uniform base + lane*16B.
__device__ __forceinline__ void gload_lds16(const u16* g, u16* l){
  __builtin_amdgcn_global_load_lds(
      (const __attribute__((address_space(1))) u32*)(g),
      (__attribute__((address_space(3))) u32*)(l),
      16, 0, 0);
}

struct F8 { float v[8]; };
__device__ __forceinline__ F8 load8f(const float* p){
  float4 a = *(const float4*)p; float4 b = *(const float4*)(p + 4);
  F8 r; r.v[0]=a.x; r.v[1]=a.y; r.v[2]=a.z; r.v[3]=a.w;
  r.v[4]=b.x; r.v[5]=b.y; r.v[6]=b.z; r.v[7]=b.w; return r;
}

#define PRE_STRIDE 4624

// ============ k0 phase A: mlp_s (2->256->2) + residual -> GT1 ==============
__global__ __launch_bounds__(256) void k0a_mlps(
    const float* __restrict__ gtok,
    const float* __restrict__ ws1_w, const float* __restrict__ ws1_b,
    const float* __restrict__ ws2_w, const float* __restrict__ ws2_b,
    float* __restrict__ GT1)
{
  __shared__ float sw1[256][2]; __shared__ float sb1[256];
  __shared__ float sw2[2][256];
  const int b = blockIdx.x;
  const int t = threadIdx.x;
  sw1[t][0] = ws1_w[2*t]; sw1[t][1] = ws1_w[2*t+1];
  sb1[t] = ws1_b[t];
  sw2[0][t] = ws2_w[t]; sw2[1][t] = ws2_w[256+t];
  __syncthreads();
  const int j = blockIdx.y*256 + t;
  const float a0 = gtok[b*1024 + 2*j], a1 = gtok[b*1024 + 2*j + 1];
  float s0 = ws2_b[0], s1 = ws2_b[1];
  #pragma unroll 4
  for (int o = 0; o < 256; ++o){
    float h = gelu_f(sw1[o][0]*a0 + sw1[o][1]*a1 + sb1[o]);
    s0 += sw2[0][o]*h; s1 += sw2[1][o]*h;
  }
  GT1[b*1024 + 2*j]     = a0 + s0;
  GT1[b*1024 + 2*j + 1] = a1 + s1;
}

// ============ k0 phase B: fc1 of mlp_c (512->2048) -> HID ==================
__global__ __launch_bounds__(256) void k0b_fc1(
    const float* __restrict__ GT1,
    const float* __restrict__ wc1_w, const float* __restrict__ wc1_b,
    float* __restrict__ HID)
{
  __shared__ float g[1024];
  const int b = blockIdx.x;
  const int t = threadIdx.x;
  for (int i = t; i < 1024; i += 256) g[i] = GT1[b*1024 + i];
  __syncthreads();
  const int o = blockIdx.y*256 + t;
  const float* wr = wc1_w + (size_t)o*512;
  float acc0 = wc1_b[o], acc1 = acc0;
  for (int d = 0; d < 512; d += 8){
    F8 w = load8f(wr + d);
    #pragma unroll
    for (int i = 0; i < 8; ++i){
      acc0 += w.v[i]*g[(d+i)*2];
      acc1 += w.v[i]*g[(d+i)*2+1];
    }
  }
  HID[b*4096 + o]        = gelu_f(acc0);
  HID[b*4096 + 2048 + o] = gelu_f(acc1);
}

// ============ k0 phase C: fc2 of mlp_c (2048->512) + residual -> GT2 =======
__global__ __launch_bounds__(256) void k0c_fc2(
    const float* __restrict__ GT1, const float* __restrict__ HID,
    const float* __restrict__ wc2_w, const float* __restrict__ wc2_b,
    float* __restrict__ GT2)
{
  __shared__ float h0[2048], h1[2048];
  const int b = blockIdx.x;
  const int t = threadIdx.x;
  for (int i = t; i < 2048; i += 256){
    h0[i] = HID[b*4096 + i]; h1[i] = HID[b*4096 + 2048 + i];
  }
  __syncthreads();
  const int d = blockIdx.y*256 + t;
  const float* wr = wc2_w + (size_t)d*2048;
  float acc0 = wc2_b[d], acc1 = acc0;
  for (int o = 0; o < 2048; o += 8){
    F8 w = load8f(wr + o);
    #pragma unroll
    for (int i = 0; i < 8; ++i){
      acc0 += w.v[i]*h0[o+i];
      acc1 += w.v[i]*h1[o+i];
    }
  }
  GT2[b*1024 + 2*d]     = GT1[b*1024 + 2*d]     + acc0;
  GT2[b*1024 + 2*d + 1] = GT1[b*1024 + 2*d + 1] + acc1;
}

// ============ k0 phase D: k,v -> dk, dv, v1l ================================
__global__ __launch_bounds__(256) void k0d_kv(
    const float* __restrict__ GT2,
    const float* __restrict__ k_w,
    const float* __restrict__ v_w, const float* __restrict__ v_b,
    float* __restrict__ DK, float* __restrict__ DV, float* __restrict__ V1L)
{
  __shared__ float g[1024];
  const int b = blockIdx.x;
  const int t = threadIdx.x;
  for (int i = t; i < 1024; i += 256) g[i] = GT2[b*1024 + i];
  __syncthreads();
  const int c = blockIdx.y*256 + t;
  const float* kr = k_w + (size_t)c*512;
  const float* vr = v_w + (size_t)c*512;
  float k0a=0.f,k1a=0.f,v0a=0.f,v1a=0.f;
  for (int d = 0; d < 512; d += 8){
    F8 kw = load8f(kr + d); F8 vw = load8f(vr + d);
    #pragma unroll
    for (int i = 0; i < 8; ++i){
      float g0 = g[(d+i)*2], g1 = g[(d+i)*2+1];
      k0a += kw.v[i]*g0; k1a += kw.v[i]*g1;
      v0a += vw.v[i]*g0; v1a += vw.v[i]*g1;
    }
  }
  DK[b*512 + c]  = k0a - k1a;
  DV[b*512 + c]  = v0a - v1a;
  V1L[b*512 + c] = v1a + v_b[c];
}

// ============ k0 phase E: wdiff + beta4 -> PRE ==============================
__global__ __launch_bounds__(256) void k0e_qpre(
    const float* __restrict__ DK,
    const float* __restrict__ q_w, const float* __restrict__ q_b,
    float* __restrict__ PRE)
{
  __shared__ float dkl[512];
  const int b = blockIdx.x;
  const int t = threadIdx.x;
  for (int i = t; i < 512; i += 256) dkl[i] = DK[b*512 + i];
  __syncthreads();
  const int i = blockIdx.y*256 + t;
  float w0=0.f,w1=0.f,w2=0.f,w3=0.f;
  for (int c = 0; c < 512; c += 4){
    w0 += dkl[c]  *q_w[(size_t)(c)  *512 + i];
    w1 += dkl[c+1]*q_w[(size_t)(c+1)*512 + i];
    w2 += dkl[c+2]*q_w[(size_t)(c+2)*512 + i];
    w3 += dkl[c+3]*q_w[(size_t)(c+3)*512 + i];
  }
  float* P = PRE + (size_t)b * PRE_STRIDE;
  P[0*512+i]=w0; P[1*512+i]=w1; P[2*512+i]=w2; P[3*512+i]=w3;
  if (blockIdx.y == 0 && t < 4){
    float bsum = 0.f;
    for (int c = t; c < 512; c += 4) bsum += dkl[c]*q_b[c];
    P[2048 + t] = bsum;
  }
}

// ============ k0 phase F: base + M -> PRE ===================================
__global__ __launch_bounds__(256) void k0f_mpre(
    const float* __restrict__ DV, const float* __restrict__ V1L,
    const float* __restrict__ merge_w, const float* __restrict__ merge_b,
    float* __restrict__ PRE)
{
  __shared__ float dvl[512], v1ll[512];
  const int b = blockIdx.x;
  const int t = threadIdx.x;
  for (int i = t; i < 512; i += 256){
    dvl[i] = DV[b*512 + i]; v1ll[i] = V1L[b*512 + i];
  }
  __syncthreads();
  const int r = blockIdx.y*256 + t;
  const float* mw = merge_w + (size_t)r*512;
  float ab = merge_b[r];
  float mh[4] = {0.f,0.f,0.f,0.f};
  for (int c = 0; c < 512; c += 8){
    F8 w = load8f(mw + c);
    #pragma unroll
    for (int i = 0; i < 8; ++i){
      ab += w.v[i]*v1ll[c+i];
      mh[i&3] += w.v[i]*dvl[c+i];
    }
  }
  float* P = PRE + (size_t)b * PRE_STRIDE;
  P[2064 + r] = ab;
  *(float4*)&P[2576 + r*4] = make_float4(mh[0],mh[1],mh[2],mh[3]);
}

// ---------------- convert fp32 -> bf16 (flat) ------------------------------
__global__ __launch_bounds__(256) void kcvt(const float* __restrict__ s,
                                            u16* __restrict__ d, int n8)
{
  int g = blockIdx.x*256 + threadIdx.x;
  if (g >= n8) return;
  F8 v = load8f(s + (size_t)g*8);
  u16 o[8];
  #pragma unroll
  for (int i=0;i<8;++i) o[i] = f2bf(v.v[i]);
  *(uint4*)(d + (size_t)g*8) = *(uint4*)o;
}

// ------- build Wg64 [64][1024] = [g1_w | g1_w] bf16 ------------------------
__global__ __launch_bounds__(256) void kcvt_dup(const float* __restrict__ g1w,
                                                u16* __restrict__ out)
{
  int idx = blockIdx.x*256 + threadIdx.x;      // 65536 total
  int r = idx >> 10, k = idx & 1023;
  out[idx] = f2bf(g1w[r*512 + (k & 511)]);
}

// ---- K1: one pass over x: XYbT[j][0..511]=x bf16, [512..1023]=attn+LN(n0) --
// 64 cols/block, 4-way channel split. Stores in 64B full-line bursts.
__global__ __launch_bounds__(256) void k1_fused(
    const float* __restrict__ x, const float* __restrict__ PRE,
    const float* __restrict__ n0_g, const float* __restrict__ n0_b,
    int j0_global, u16* __restrict__ XYbT)
{
  __shared__ float wd[4][512];
  __shared__ float bs[512];
  __shared__ float Mm[512][4];
  __shared__ float gam[512], bet[512];
  __shared__ float beta4[4];
  __shared__ float part[4][4][64];
  __shared__ float pstat[2][4][64];
  const int tid = threadIdx.x;
  const int cid = tid & 63;
  const int qtr = tid >> 6;
  const int jl = blockIdx.x*64 + cid;
  const int jg = j0_global + jl;
  const int b = jg >> 12, n = jg & 4095;   // 4096 % 64 == 0: no b-straddle
  const float* P = PRE + (size_t)b * PRE_STRIDE;
  for (int i = tid; i < 2048; i += 256) wd[i>>9][i&511] = P[i];
  if (tid < 4) beta4[tid] = P[2048 + tid];
  for (int i = tid; i < 512; i += 256){
    bs[i] = P[2064 + i]; gam[i] = n0_g[i]; bet[i] = n0_b[i];
  }
  for (int i = tid; i < 2048; i += 256) Mm[i>>2][i&3] = P[2576 + i];
  __syncthreads();
  const float* xc = x + (size_t)b*2097152 + n;
  u16* col = XYbT + (size_t)jl*1024;
  const int ibase = qtr*128;
  float l0=0.f, l1=0.f, l2=0.f, l3=0.f;
  for (int i0 = 0; i0 < 128; i0 += 32){
    u16 ob[32];
    #pragma unroll
    for (int m = 0; m < 32; ++m){
      int i = ibase + i0 + m;
      float xv = xc[(size_t)i*4096];
      ob[m] = f2bf(xv);
      l0 += wd[0][i]*xv; l1 += wd[1][i]*xv;
      l2 += wd[2][i]*xv; l3 += wd[3][i]*xv;
    }
    #pragma unroll
    for (int q = 0; q < 4; ++q)            // one full 64B line, back-to-back
      *(uint4*)&col[ibase + i0 + 8*q] = *(uint4*)&ob[8*q];
  }
  part[0][qtr][cid] = l0; part[1][qtr][cid] = l1;
  part[2][qtr][cid] = l2; part[3][qtr][cid] = l3;
  __syncthreads();
  l0 = part[0][0][cid] + part[0][1][cid] + part[0][2][cid] + part[0][3][cid] + beta4[0];
  l1 = part[1][0][cid] + part[1][1][cid] + part[1][2][cid] + part[1][3][cid] + beta4[1];
  l2 = part[2][0][cid] + part[2][1][cid] + part[2][2][cid] + part[2][3][cid] + beta4[2];
  l3 = part[3][0][cid] + part[3][1][cid] + part[3][2][cid] + part[3][3][cid] + beta4[3];
  const float sc = 0.0883883476483184405f;
  float p0 = 1.f/(1.f+expf(-sc*l0));
  float p1 = 1.f/(1.f+expf(-sc*l1));
  float p2 = 1.f/(1.f+expf(-sc*l2));
  float p3 = 1.f/(1.f+expf(-sc*l3));
  float s=0.f, s2=0.f;
  for (int c = ibase; c < ibase + 128; ++c){
    float m = bs[c] + Mm[c][0]*p0 + Mm[c][1]*p1 + Mm[c][2]*p2 + Mm[c][3]*p3;
    s += m; s2 += m*m;
  }
  pstat[0][qtr][cid] = s; pstat[1][qtr][cid] = s2;
  __syncthreads();
  s  = pstat[0][0][cid] + pstat[0][1][cid] + pstat[0][2][cid] + pstat[0][3][cid];
  s2 = pstat[1][0][cid] + pstat[1][1][cid] + pstat[1][2][cid] + pstat[1][3][cid];
  float mean = s*(1.f/512.f);
  float rs = rsqrtf(s2*(1.f/512.f) - mean*mean + 1e-5f);
  for (int c0 = 0; c0 < 128; c0 += 32){
    u16 ob[32];
    #pragma unroll
    for (int m = 0; m < 32; ++m){
      int c = ibase + c0 + m;
      float v = bs[c] + Mm[c][0]*p0 + Mm[c][1]*p1 + Mm[c][2]*p2 + Mm[c][3]*p3;
      ob[m] = f2bf((v - mean)*rs*gam[c] + bet[c]);
    }
    #pragma unroll
    for (int q = 0; q < 4; ++q)            // full 64B line, back-to-back
      *(uint4*)&col[512 + ibase + c0 + 8*q] = *(uint4*)&ob[8*q];
  }
}

// --------- MFMA GEMM: 512 threads, 8 waves (2x4), same 128x128 tile --------
// Same verified 3-buffer depth-2 two-barrier schedule + T2 swizzle + setprio,
// but 8 waves x 64x32 sub-tiles (acc[4][2], ~32 acc VGPR -> under the 64-VGPR
// occupancy step). LDS unchanged 48KB -> still 3 blocks/CU, now 24 waves/CU
// (was 12): doubles cross-wave latency hiding at constant sync structure.
// Per wave per K-step: 1 A-DMA + 1 B-DMA (vmcnt 4/2/0), 8 MFMA.
__global__ __launch_bounds__(512) void mfma_gemm_p(
    const u16* __restrict__ Wb, const float* __restrict__ bias,
    const u16* __restrict__ XT, int K, int M,
    u16* __restrict__ Out, int do_gelu, int log2nbi)
{
  __shared__ __align__(16) u16 SH[3][8192];  // per buf: A[128][32] | B[128][32]
  const int tid = threadIdx.x;
  const int lane = tid & 63;
  const int wv = __builtin_amdgcn_readfirstlane(tid >> 6);   // 0..7
  const int id = blockIdx.x;
  const int bi = (id >> 3) & ((1 << log2nbi) - 1);
  const int bj = (id & 7) + 8 * (id >> (3 + log2nbi));
  const int roff = (wv >> 2) * 64;        // 2 row-halves
  const int noff = (wv & 3) * 32;         // 4 col-quadrants
  const int lm = lane & 15, quad = lane >> 4;
  const int qs = (quad ^ ((lm >> 1) & 3)) * 8;   // swizzled 16B slot (read)

  f32x4 acc[4][2];
  #pragma unroll
  for (int i=0;i<4;++i){
    #pragma unroll
    for (int j=0;j<2;++j) acc[i][j] = (f32x4){0.f,0.f,0.f,0.f};
  }

  // DMA map: wave wv stages A rows [wv*16,+16) and B rows [wv*16,+16);
  // lane>>2 -> row-in-16, lane&3 -> 16B k-chunk (global slot pre-swizzled
  // by (row>>1)&3 = (lane>>3)&3 so the linear LDS write lands swizzled).
  const int r16 = lane >> 2;
  const int kc  = (((lane & 3) ^ ((lane >> 3) & 3))) * 8;
  const u16* aG = Wb + (size_t)(bi*128 + wv*16 + r16)*K + kc;
  const u16* bG = XT + (size_t)(bj*128 + wv*16 + r16)*1024 + kc;
  const int aOff = wv*512;           // (wv*16)*32 u16
  const int bOff = 4096 + wv*512;

#define GP_STAGE(base, kk) do { \
    gload_lds16(aG + (kk), (base) + aOff); \
    gload_lds16(bG + (kk), (base) + bOff); \
  } while(0)

#define GP_COMPUTE(base) do { \
    bfrag av[4], bv[2]; \
    _Pragma("unroll") \
    for (int i=0;i<4;++i) \
      av[i] = *(const bfrag*)&(base)[(roff + 16*i + lm)*32 + qs]; \
    _Pragma("unroll") \
    for (int j=0;j<2;++j) \
      bv[j] = *(const bfrag*)&(base)[4096 + (noff + 16*j + lm)*32 + qs]; \
    __builtin_amdgcn_s_setprio(1); \
    _Pragma("unroll") \
    for (int i=0;i<4;++i){ \
      _Pragma("unroll") \
      for (int j=0;j<2;++j) \
        acc[i][j] = __builtin_amdgcn_mfma_f32_16x16x32_bf16(av[i], bv[j], acc[i][j], 0,0,0); \
    } \
    __builtin_amdgcn_s_setprio(0); \
  } while(0)

  u16* b0 = &SH[0][0];
  u16* b1 = &SH[1][0];
  u16* b2 = &SH[2][0];
  GP_STAGE(b0, 0);
  GP_STAGE(b1, 32);
  for (int k0 = 0; k0 + 64 < K; k0 += 32){
    GP_STAGE(b2, k0 + 64);                       // prefetch 2 tiles ahead
    asm volatile("s_waitcnt vmcnt(4)" ::: "memory");  // tile k0 resident
    __builtin_amdgcn_s_barrier();
    __builtin_amdgcn_sched_barrier(0);
    GP_COMPUTE(b0);
    __builtin_amdgcn_sched_barrier(0);
    __builtin_amdgcn_s_barrier();                // reads done before overwrite
    u16* t = b0; b0 = b1; b1 = b2; b2 = t;
  }
  asm volatile("s_waitcnt vmcnt(2)" ::: "memory");
  __builtin_amdgcn_s_barrier();
  __builtin_amdgcn_sched_barrier(0);
  GP_COMPUTE(b0);
  asm volatile("s_waitcnt vmcnt(0)" ::: "memory");
  __builtin_amdgcn_s_barrier();
  __builtin_amdgcn_sched_barrier(0);
  GP_COMPUTE(b1);
  __syncthreads();
#undef GP_STAGE
#undef GP_COMPUTE

  // single-pass epilogue: 8 waves write disjoint 64x32 regions of 128x136
  u16* Tt = &SH[0][0];                 // 128*136 = 17408 u16 <= 24576
  #pragma unroll
  for (int i=0;i<4;++i){
    float4 bb = *(const float4*)&bias[bi*128 + roff + 16*i + quad*4];
    float b4[4] = {bb.x,bb.y,bb.z,bb.w};
    #pragma unroll
    for (int j=0;j<2;++j){
      int colr = noff + 16*j + lm;
      #pragma unroll
      for (int s2=0;s2<2;++s2){
        float v0 = acc[i][j][2*s2]   + b4[2*s2];
        float v1 = acc[i][j][2*s2+1] + b4[2*s2+1];
        if (do_gelu){ v0 = gelu_f(v0); v1 = gelu_f(v1); }
        unsigned int dw = (unsigned int)f2bf(v0) | ((unsigned int)f2bf(v1) << 16);
        *(unsigned int*)&Tt[colr*136 + roff + 16*i + quad*4 + 2*s2] = dw;
      }
    }
  }
  __syncthreads();
  {
    int c = tid >> 2, q = tid & 3;     // col 0..127, 32-u16 quarter
    u16* dst = Out + (size_t)(bj*128 + c)*M + bi*128 + q*32;
    const u16* src = &Tt[c*136 + q*32];
    #pragma unroll
    for (int m=0;m<2;++m){
      *(uint4*)(dst + m*8)      = *(const uint4*)(src + m*8);
      *(uint4*)(dst + 16 + m*8) = *(const uint4*)(src + 16 + m*8);
    }
  }
}

// ---- MFMA g1 GEMM + FUSED HEAD (T2 swizzle, round-10 loop, setprio) -------
__global__ __launch_bounds__(256) void mfma_g64h(
    const u16* __restrict__ Wg, const float* __restrict__ bias,
    const u16* __restrict__ XT,
    const float* __restrict__ gl1_g, const float* __restrict__ gl1_b,
    const float* __restrict__ g2_w, const float* __restrict__ g2_b,
    const float* __restrict__ gl2_g, const float* __restrict__ gl2_b,
    const float* __restrict__ g3_w, const float* __restrict__ g3_b,
    const float* __restrict__ gl3_g, const float* __restrict__ gl3_b,
    const float* __restrict__ g4_w, const float* __restrict__ g4_b, int has_g4b,
    float* __restrict__ Outp, int j0_global)
{
  __shared__ __align__(16) u16 SH[3][6144];  // per buf: A[64][32] | B[128][32]
  const int tid = threadIdx.x;
  const int lane = tid & 63;
  const int wv = __builtin_amdgcn_readfirstlane(tid >> 6);
  const int bj = blockIdx.x;
  const int lm = lane & 15, quad = lane >> 4;
  const int qs = (quad ^ ((lm >> 1) & 3)) * 8;   // swizzled 16B slot (read)

  f32x4 acc[4][2];
  #pragma unroll
  for (int i=0;i<4;++i){
    #pragma unroll
    for (int j=0;j<2;++j) acc[i][j] = (f32x4){0.f,0.f,0.f,0.f};
  }
  const int r16 = lane >> 2;
  const int kc  = (((lane & 3) ^ ((lane >> 3) & 3))) * 8;
  const u16* aG = Wg + (size_t)(wv*16 + r16)*1024 + kc;
  const u16* bG = XT + (size_t)(bj*128 + wv*32 + r16)*1024 + kc;
  const int aOff = wv*512;            // (wv*16)*32
  const int bOff = 2048 + wv*1024;    // B area + (wv*32)*32

#define G64_STAGE(base, kk) do { \
    gload_lds16(aG + (kk),             (base) + aOff); \
    gload_lds16(bG + (kk),             (base) + bOff); \
    gload_lds16(bG + 16*1024 + (kk),   (base) + bOff + 512); \
  } while(0)

#define G64_COMPUTE(base) do { \
    bfrag av[4], bv[2]; \
    _Pragma("unroll") \
    for (int i=0;i<4;++i) \
      av[i] = *(const bfrag*)&(base)[(16*i + lm)*32 + qs]; \
    _Pragma("unroll") \
    for (int j=0;j<2;++j) \
      bv[j] = *(const bfrag*)&(base)[2048 + (wv*32 + 16*j + lm)*32 + qs]; \
    __builtin_amdgcn_s_setprio(1); \
    _Pragma("unroll") \
    for (int i=0;i<4;++i){ \
      _Pragma("unroll") \
      for (int j=0;j<2;++j) \
        acc[i][j] = __builtin_amdgcn_mfma_f32_16x16x32_bf16(av[i], bv[j], acc[i][j], 0,0,0); \
    } \
    __builtin_amdgcn_s_setprio(0); \
  } while(0)

  u16* b0 = &SH[0][0];
  u16* b1 = &SH[1][0];
  u16* b2 = &SH[2][0];
  G64_STAGE(b0, 0);
  G64_STAGE(b1, 32);
  for (int k0 = 0; k0 + 64 < 1024; k0 += 32){
    G64_STAGE(b2, k0 + 64);
    asm volatile("s_waitcnt vmcnt(6)" ::: "memory");
    __builtin_amdgcn_s_barrier();
    __builtin_amdgcn_sched_barrier(0);
    G64_COMPUTE(b0);
    __builtin_amdgcn_sched_barrier(0);
    __builtin_amdgcn_s_barrier();
    u16* t = b0; b0 = b1; b1 = b2; b2 = t;
  }
  asm volatile("s_waitcnt vmcnt(3)" ::: "memory");
  __builtin_amdgcn_s_barrier();
  __builtin_amdgcn_sched_barrier(0);
  G64_COMPUTE(b0);
  asm volatile("s_waitcnt vmcnt(0)" ::: "memory");
  __builtin_amdgcn_s_barrier();
  __builtin_amdgcn_sched_barrier(0);
  G64_COMPUTE(b1);
  __syncthreads();
#undef G64_STAGE
#undef G64_COMPUTE

  // stage raw g1 [128 cols][64 ch] (stride 72) into SH
  u16* Tg = &SH[0][0];                 // 128*72 = 9216 u16 = 18KB
  #pragma unroll
  for (int i=0;i<4;++i){
    float4 bb = *(const float4*)&bias[16*i + quad*4];
    float b4[4] = {bb.x,bb.y,bb.z,bb.w};
    #pragma unroll
    for (int j=0;j<2;++j){
      int col = wv*32 + 16*j + lm;
      #pragma unroll
      for (int s2=0;s2<2;++s2){
        float v0 = acc[i][j][2*s2]   + b4[2*s2];
        float v1 = acc[i][j][2*s2+1] + b4[2*s2+1];
        unsigned int dw = (unsigned int)f2bf(v0) | ((unsigned int)f2bf(v1) << 16);
        *(unsigned int*)&Tg[col*72 + 16*i + quad*4 + 2*s2] = dw;
      }
    }
  }
  // stage head weights into LDS above Tg (byte off 18432; 1281 floats = 5KB)
  float* HW = (float*)(&SH[0][0] + 9216);
  if (tid < 64){ HW[tid] = gl1_g[tid]; HW[64+tid] = gl1_b[tid]; }
  for (int i = tid; i < 1024; i += 256) HW[128+i] = g2_w[i];
  if (tid < 16){ HW[1152+tid]=g2_b[tid]; HW[1168+tid]=gl2_g[tid]; HW[1184+tid]=gl2_b[tid]; }
  if (tid >= 64 && tid < 128) HW[1200 + tid-64] = g3_w[tid-64];
  if (tid >= 128 && tid < 132){
    int q = tid - 128;
    HW[1264+q]=g3_b[q]; HW[1268+q]=gl3_g[q]; HW[1272+q]=gl3_b[q];
    HW[1276+q] = g4_w[q] - g4_w[4+q];
  }
  if (tid == 132) HW[1280] = has_g4b ? (g4_b[0] - g4_b[1]) : 0.f;
  __syncthreads();

  if (tid < 128){
    const u16* gc = &Tg[tid*72];
    float a1[64]; float s=0.f;
    #pragma unroll
    for (int c0=0;c0<64;c0+=8){
      uint4 w = *(const uint4*)(gc + c0);
      const u16* wp = (const u16*)&w;
      #pragma unroll
      for (int m=0;m<8;++m){ a1[c0+m] = bf2f(wp[m]); s += a1[c0+m]; }
    }
    float m = s*(1.f/64.f); float s2=0.f;
    #pragma unroll
    for (int c=0;c<64;++c){ float d=a1[c]-m; s2+=d*d; }
    float rs = rsqrtf(s2*(1.f/64.f)+1e-5f);
    #pragma unroll
    for (int c=0;c<64;++c) a1[c] = gelu_f((a1[c]-m)*rs*HW[c]+HW[64+c]);

    float a2[16]; s=0.f;
    #pragma unroll
    for (int i=0;i<16;++i){
      float acc2 = HW[1152+i];
      #pragma unroll
      for (int o=0;o<64;++o) acc2 += HW[128 + i*64 + o]*a1[o];
      a2[i]=acc2; s+=acc2;
    }
    m = s*(1.f/16.f); s2=0.f;
    #pragma unroll
    for (int i=0;i<16;++i){ float d=a2[i]-m; s2+=d*d; }
    rs = rsqrtf(s2*(1.f/16.f)+1e-5f);
    float a2g[16];
    #pragma unroll
    for (int i=0;i<16;++i) a2g[i] = gelu_f((a2[i]-m)*rs*HW[1168+i]+HW[1184+i]);

    float a3[4]; s=0.f;
    #pragma unroll
    for (int i=0;i<4;++i){
      float acc3 = HW[1264+i];
      #pragma unroll
      for (int o=0;o<16;++o) acc3 += HW[1200 + i*16 + o]*a2g[o];
      a3[i]=acc3; s+=acc3;
    }
    m = s*0.25f; s2=0.f;
    #pragma unroll
    for (int i=0;i<4;++i){ float d=a3[i]-m; s2+=d*d; }
    rs = rsqrtf(s2*0.25f+1e-5f);
    float z = HW[1280];
    #pragma unroll
    for (int i=0;i<4;++i) z += HW[1276+i]*gelu_f((a3[i]-m)*rs*HW[1268+i]+HW[1272+i]);
    Outp[j0_global + bj*128 + tid] = 1.f/(1.f+expf(-z));
  }
}

// ---- LN over 512 ch, wave-per-column; bf16 in, bf16 out into XYbT y-half --
__global__ __launch_bounds__(256) void k_lnT(
    const u16* __restrict__ t2T,
    const float* __restrict__ gamma, const float* __restrict__ beta,
    u16* __restrict__ XYbT)
{
  __shared__ float gam[512], bet[512];
  const int tid = threadIdx.x;
  for (int c = tid; c < 512; c += 256){ gam[c]=gamma[c]; bet[c]=beta[c]; }
  __syncthreads();
  const int lane = tid & 63, wv = tid >> 6;
  const int j = blockIdx.x*4 + wv;
  uint4 w = *(const uint4*)(t2T + (size_t)j*512 + lane*8);
  const u16* wp = (const u16*)&w;
  float vv[8];
  #pragma unroll
  for (int m=0;m<8;++m) vv[m] = bf2f(wp[m]);
  float s = 0.f, s2 = 0.f;
  #pragma unroll
  for (int m=0;m<8;++m){ s += vv[m]; s2 += vv[m]*vv[m]; }
  #pragma unroll
  for (int off = 32; off; off >>= 1){
    s  += __shfl_xor(s,  off, 64);
    s2 += __shfl_xor(s2, off, 64);
  }
  float mean = s*(1.f/512.f);
  float rs = rsqrtf(s2*(1.f/512.f) - mean*mean + 1e-5f);
  u16 ob[8];
  #pragma unroll
  for (int m=0;m<8;++m){
    int c = lane*8 + m;
    ob[m] = f2bf((vv[m]-mean)*rs*gam[c] + bet[c]);
  }
  *(uint4*)&XYbT[(size_t)j*1024 + 512 + lane*8] = *(uint4*)ob;
}

extern "C" void kernel_launch(void* const* d_in, const int* in_sizes, int n_in,
                              void* d_out, int out_size, void* d_ws, size_t ws_size,
                              hipStream_t stream)
{
  const float* gtok  = (const float*)d_in[0];
  const float* x     = (const float*)d_in[1];
  const float* ws1_w = (const float*)d_in[2];
  const float* ws1_b = (const float*)d_in[3];
  const float* ws2_w = (const float*)d_in[4];
  const float* ws2_b = (const float*)d_in[5];
  const float* wc1_w = (const float*)d_in[6];
  const float* wc1_b = (const float*)d_in[7];
  const float* wc2_w = (const float*)d_in[8];
  const float* wc2_b = (const float*)d_in[9];
  const float* q_w   = (const float*)d_in[10];
  const float* q_b   = (const float*)d_in[11];
  const float* k_w   = (const float*)d_in[12];
  const float* v_w   = (const float*)d_in[14];
  const float* v_b   = (const float*)d_in[15];
  const float* merge_w = (const float*)d_in[16];
  const float* merge_b = (const float*)d_in[17];
  const float* m1_w  = (const float*)d_in[18];
  const float* m1_b  = (const float*)d_in[19];
  const float* m2_w  = (const float*)d_in[20];
  const float* m2_b  = (const float*)d_in[21];
  const float* n0_g  = (const float*)d_in[22];
  const float* n0_b  = (const float*)d_in[23];
  const float* n1_g  = (const float*)d_in[24];
  const float* n1_b  = (const float*)d_in[25];
  const float* g1_w  = (const float*)d_in[26];
  const float* g1_b  = (const float*)d_in[27];
  const float* gl1_g = (const float*)d_in[28];
  const float* gl1_b = (const float*)d_in[29];
  const float* g2_w  = (const float*)d_in[30];
  const float* g2_b  = (const float*)d_in[31];
  const float* gl2_g = (const float*)d_in[32];
  const float* gl2_b = (const float*)d_in[33];
  const float* g3_w  = (const float*)d_in[34];
  const float* g3_b  = (const float*)d_in[35];
  const float* gl3_g = (const float*)d_in[36];
  const float* gl3_b = (const float*)d_in[37];
  const float* g4_w  = (const float*)d_in[38];
  const float* g4_b  = (n_in > 39) ? (const float*)d_in[39] : nullptr;

  const int TOT = 65536;
  const size_t PRE_BYTES = (size_t)16 * PRE_STRIDE * 4;
  const size_t GT1_B = 65536, HID_B = 262144, GT2_B = 65536;
  const size_t DK_B = 32768, DV_B = 32768, V1L_B = 32768;
  const size_t WB1_B = (size_t)1024*1024*2;
  const size_t WB2_B = (size_t)512*1024*2;
  const size_t WG_B  = (size_t)64*1024*2;
  const size_t FIXED = PRE_BYTES + GT1_B + HID_B + GT2_B + DK_B + DV_B + V1L_B
                     + WB1_B + WB2_B + WG_B;
  // per-chunk: XYbT 2048C + T1bT 2048C + T2bT 1024C = 5120C bytes
  int C = 65536;
  while (C > 4096 && FIXED + (size_t)5120*C > ws_size) C >>= 1;
  const int nch = TOT / C;

  char* wsb = (char*)d_ws;
  size_t off = 0;
  float* PRE = (float*)(wsb + off); off += PRE_BYTES;
  float* GT1 = (float*)(wsb + off); off += GT1_B;
  float* HID = (float*)(wsb + off); off += HID_B;
  float* GT2 = (float*)(wsb + off); off += GT2_B;
  float* DK  = (float*)(wsb + off); off += DK_B;
  float* DV  = (float*)(wsb + off); off += DV_B;
  float* V1L = (float*)(wsb + off); off += V1L_B;
  u16* Wb1   = (u16*)(wsb + off);   off += WB1_B;
  u16* Wb2   = (u16*)(wsb + off);   off += WB2_B;
  u16* Wg    = (u16*)(wsb + off);   off += WG_B;
  u16* XYbT  = (u16*)(wsb + off);   off += (size_t)2048*C;  // [C][1024] bf16
  u16* T1bT  = (u16*)(wsb + off);   off += (size_t)2048*C;  // [C][1024] bf16
  u16* T2bT  = (u16*)(wsb + off);   off += (size_t)1024*C;  // [C][512] bf16

  dim3 blk(256);
  dim3 blk5(512);
  hipLaunchKernelGGL(kcvt, dim3(512), blk, 0, stream, m1_w, Wb1, 1024*1024/8);
  hipLaunchKernelGGL(kcvt, dim3(256), blk, 0, stream, m2_w, Wb2, 512*1024/8);
  hipLaunchKernelGGL(kcvt_dup, dim3(256), blk, 0, stream, g1_w, Wg);
  hipLaunchKernelGGL(k0a_mlps, dim3(16,2), blk, 0, stream,
      gtok, ws1_w, ws1_b, ws2_w, ws2_b, GT1);
  hipLaunchKernelGGL(k0b_fc1, dim3(16,8), blk, 0, stream, GT1, wc1_w, wc1_b, HID);
  hipLaunchKernelGGL(k0c_fc2, dim3(16,2), blk, 0, stream, GT1, HID, wc2_w, wc2_b, GT2);
  hipLaunchKernelGGL(k0d_kv,  dim3(16,2), blk, 0, stream, GT2, k_w, v_w, v_b, DK, DV, V1L);
  hipLaunchKernelGGL(k0e_qpre, dim3(16,2), blk, 0, stream, DK, q_w, q_b, PRE);
  hipLaunchKernelGGL(k0f_mpre, dim3(16,2), blk, 0, stream, DV, V1L, merge_w, merge_b, PRE);

  for (int ch = 0; ch < nch; ++ch){
    const int j0 = ch * C;
    // x->bf16 + attn + merge + LN(n0) in one pass over x -> XYbT
    hipLaunchKernelGGL(k1_fused, dim3(C/64), blk, 0, stream,
        x, PRE, n0_g, n0_b, j0, XYbT);
    // t1 = gelu(m1 @ XY + b) -> T1bT  (M=1024, nbi=8)
    hipLaunchKernelGGL(mfma_gemm_p, dim3(8*(C/128)), blk5, 0, stream,
        Wb1, m1_b, XYbT, 1024, 1024, T1bT, 1, 3);
    // t2 = m2 @ t1 + b -> T2bT       (M=512, nbi=4)
    hipLaunchKernelGGL(mfma_gemm_p, dim3(4*(C/128)), blk5, 0, stream,
        Wb2, m2_b, T1bT, 1024, 512, T2bT, 0, 2);
    // LN(t2; n1) -> bf16, overwrite y-half of XYbT (x-half stays = x bf16)
    hipLaunchKernelGGL(k_lnT, dim3(C/4), blk, 0, stream, T2bT, n1_g, n1_b, XYbT);
    // g1 GEMM + fused head -> d_out directly
    hipLaunchKernelGGL(mfma_g64h, dim3(C/128), blk, 0, stream,
        Wg, g1_b, XYbT,
        gl1_g, gl1_b, g2_w, g2_b, gl2_g, gl2_b,
        g3_w, g3_b, gl3_g, gl3_b,
        g4_w, g4_b ? g4_b : g4_w, g4_b ? 1 : 0, (float*)d_out, j0);
  }
}